// Round 3
// baseline (1769.326 us; speedup 1.0000x reference)
//
#include <hip/hip_runtime.h>
#include <hip/hip_bf16.h>

#define EPS 1e-5f

static constexpr int Bv = 64, Tv = 512, Vv = 17, Hv = 128;
static constexpr int CHv = Hv * Vv;                // 2176
static constexpr long ZBv = (long)CHv * Tv;        // 1114112 elems per batch

typedef __attribute__((ext_vector_type(8))) short short8v;
typedef __attribute__((ext_vector_type(4))) float f32x4;

// ---- primary (MFMA) workspace layout ----
static constexpr size_t SZ_Z    = (size_t)Bv * (size_t)ZBv * 2;      // 142,606,336
static constexpr size_t OFF_Z   = 0;                                  // pre-BN2 z [b][ci][sf]; later aliased by cp
static constexpr size_t OFF_ZR  = OFF_Z + SZ_Z;                       // post-BN2 zr [b][sf][ci]
static constexpr size_t OFF_WKT = OFF_ZR + SZ_Z;                      // bf16 [k][o][ci]
static constexpr size_t SZ_WKT  = (size_t)3 * 128 * 2176 * 2;        // 1,671,168
static constexpr size_t OFF_STP = OFF_WKT + SZ_WKT;
static constexpr size_t ST_FLOATS = 15232;
static constexpr size_t NEED_P  = OFF_STP + ST_FLOATS * 4;           // ~287 MB

// ---- fallback (round-0, proven <=163MB) layout ----
static constexpr size_t OFF_WTF = SZ_Z;                               // f32 wt_t [(c*3+k)][o]
static constexpr size_t SZ_WTF  = (size_t)6528 * 128 * 4;
static constexpr size_t OFF_CPF = OFF_WTF + SZ_WTF;
static constexpr size_t SZ_CP   = (size_t)Bv * Hv * Tv * 4;          // 16,777,216
static constexpr size_t OFF_STF = OFF_CPF + SZ_CP;

// stats region (floats):
//  0:s1sp[1024] 1024:ss1sp 2048:s2sp[2048] 4096:ss2sp 6144:s3sp[2048] 8192:ss3sp
//  10240:sc1[64] 10304:sh1[64] 10368:sc2[128] 10496:sh2[128] 10624:sc3[128] 10752:sh3[128]
//  10880:scc[2176] 13056:shc[2176]

__global__ __launch_bounds__(256) void k_wt_bf16(const float* __restrict__ wt,
                                                 __hip_bfloat16* __restrict__ wkt) {
    int e = blockIdx.x * 256 + threadIdx.x;   // e = (k*128+o)*2176 + c
    if (e >= 3 * 128 * 2176) return;
    int c = e % 2176;
    int ko = e / 2176;
    int o = ko % 128, k = ko / 128;
    wkt[e] = __float2bfloat16(wt[(size_t)o * 6528 + c * 3 + k]);
}

__global__ __launch_bounds__(256) void k_wt_transpose(const float* __restrict__ wt,
                                                      float* __restrict__ wt_t) {
    int e = blockIdx.x * 256 + threadIdx.x;   // e = (c*3+k)*128 + o
    if (e >= 6528 * 128) return;
    int o = e & 127, ck = e >> 7;
    wt_t[e] = wt[(size_t)o * 6528 + ck];
}

__global__ __launch_bounds__(256) void k_stats1(const float* __restrict__ x,
                                                const float* __restrict__ adj,
                                                const float* __restrict__ w1,
                                                const float* __restrict__ b1,
                                                float* __restrict__ st) {
    __shared__ float adj_s[289];
    __shared__ float xs[32 * 34];
    __shared__ float mix[32 * 34];
    __shared__ float red[256], red2[256];
    int tid = threadIdx.x;
    int n0 = blockIdx.x * 32;
    for (int i = tid; i < 289; i += 256) adj_s[i] = adj[i];
    for (int i = tid; i < 1088; i += 256) xs[i] = x[(size_t)n0 * 34 + i];
    __syncthreads();
    for (int e = tid; e < 1088; e += 256) {
        int n = e / 34, r = e % 34;
        int w = r >> 1, c = r & 1;
        float acc = 0.f;
        for (int v = 0; v < 17; ++v) acc += xs[n * 34 + v * 2 + c] * adj_s[v * 17 + w];
        mix[n * 34 + w * 2 + c] = acc;
    }
    __syncthreads();
    int o = tid & 63, g = tid >> 6;
    float w0 = w1[o * 2], w1v = w1[o * 2 + 1], bb = b1[o];
    float s = 0.f, s2 = 0.f;
    for (int n = g; n < 32; n += 4)
        for (int v = 0; v < 17; ++v) {
            float a = mix[n * 34 + v * 2] * w0 + mix[n * 34 + v * 2 + 1] * w1v + bb;
            s += a; s2 += a * a;
        }
    red[tid] = s; red2[tid] = s2;
    __syncthreads();
    if (tid < 64) {
        float S  = red[tid] + red[tid + 64] + red[tid + 128] + red[tid + 192];
        float S2 = red2[tid] + red2[tid + 64] + red2[tid + 128] + red2[tid + 192];
        int slot = blockIdx.x & 15;
        atomicAdd(&st[slot * 64 + o], S);
        atomicAdd(&st[1024 + slot * 64 + o], S2);
    }
}

__global__ void k_finalize(const float* __restrict__ sums, const float* __restrict__ sumsq,
                           const float* __restrict__ gamma, const float* __restrict__ beta,
                           float* __restrict__ scale, float* __restrict__ shift,
                           int count, float inv_denom) {
    int o = threadIdx.x;
    if (o >= count) return;
    float S = 0.f, Q = 0.f;
    for (int j = 0; j < 16; ++j) { S += sums[j * count + o]; Q += sumsq[j * count + o]; }
    float m = S * inv_denom;
    float var = Q * inv_denom - m * m;
    float rstd = rsqrtf(var + EPS);
    float sc = rstd * gamma[o];
    scale[o] = sc;
    shift[o] = beta[o] - m * sc;
}

__global__ __launch_bounds__(256) void k_expand(const float* __restrict__ sc2,
                                                const float* __restrict__ sh2,
                                                float* __restrict__ scc,
                                                float* __restrict__ shc) {
    int i = blockIdx.x * 256 + threadIdx.x;
    if (i >= 2176) return;
    int h = i / 17;
    scc[i] = sc2[h];
    shc[i] = sh2[h];
}

// processes one (b, pair of t). Writes pre-BN2 block-2 output in FOLDED conv layout:
// z[b][ci][sf] where flat index within batch = o*8704 + t*17 + v (ci = idx/512, sf = idx%512)
__global__ __launch_bounds__(256) void k_gcn(const float* __restrict__ x,
                                             const float* __restrict__ adj,
                                             const float* __restrict__ w1,
                                             const float* __restrict__ b1,
                                             const float* __restrict__ sc1,
                                             const float* __restrict__ sh1,
                                             const float* __restrict__ w2,
                                             const float* __restrict__ b2,
                                             float* __restrict__ st,
                                             __hip_bfloat16* __restrict__ zpre) {
    __shared__ float adj_s[289];
    __shared__ float xs[68];
    __shared__ float mix1[68];
    __shared__ float h1[34 * 65];    // [nv][c] padded; later aliased as bf16 a2[128][34]
    __shared__ float mix2[40 * 65];  // [nv][c] padded (rows 34..39 zero)
    __shared__ float w2s[128 * 65];  // [o][c] padded
    __shared__ float redS[8 * 128], redQ[8 * 128];

    int tid = threadIdx.x;
    int b = blockIdx.x >> 8;
    int t0 = (blockIdx.x & 255) * 2;

    for (int i = tid; i < 289; i += 256) adj_s[i] = adj[i];
    for (int i = tid; i < 68; i += 256) xs[i] = x[(size_t)(b * 512 + t0) * 34 + i];
    for (int i = tid; i < 8192; i += 256) { int o = i >> 6, c = i & 63; w2s[o * 65 + c] = w2[i]; }
    __syncthreads();

    for (int e = tid; e < 68; e += 256) {
        int n = e / 34, r = e % 34, w = r >> 1, c = r & 1;
        float acc = 0.f;
        for (int v = 0; v < 17; ++v) acc += xs[n * 34 + v * 2 + c] * adj_s[v * 17 + w];
        mix1[n * 34 + w * 2 + c] = acc;
    }
    __syncthreads();

    for (int e = tid; e < 34 * 64; e += 256) {
        int nv = e >> 6, o = e & 63;
        int n = nv / 17, v = nv - n * 17;
        float a = mix1[n * 34 + v * 2] * w1[o * 2] + mix1[n * 34 + v * 2 + 1] * w1[o * 2 + 1] + b1[o];
        a = a * sc1[o] + sh1[o];
        h1[nv * 65 + o] = fmaxf(a, 0.f);
    }
    __syncthreads();

    for (int e = tid; e < 136; e += 256) {
        int nw = e >> 2, cq = (e & 3) << 4;
        int n = nw / 17, w = nw - n * 17;
        float a[16];
#pragma unroll
        for (int i = 0; i < 16; ++i) a[i] = 0.f;
        for (int v = 0; v < 17; ++v) {
            float ad = adj_s[v * 17 + w];
            const float* hp = &h1[(n * 17 + v) * 65 + cq];
#pragma unroll
            for (int i = 0; i < 16; ++i) a[i] += ad * hp[i];
        }
        float* mp = &mix2[nw * 65 + cq];
#pragma unroll
        for (int i = 0; i < 16; ++i) mp[i] = a[i];
    }
    for (int e = tid; e < 6 * 65; e += 256) mix2[34 * 65 + e] = 0.f;
    __syncthreads();

    int og = tid & 31, ng = tid >> 5;
    int obase = og << 2, nvbase = ng * 5;
    float accs[5][4];
#pragma unroll
    for (int i = 0; i < 5; ++i)
#pragma unroll
        for (int r = 0; r < 4; ++r) accs[i][r] = 0.f;
    for (int c4 = 0; c4 < 64; c4 += 4) {
        float wv[4][4];
#pragma unroll
        for (int r = 0; r < 4; ++r)
#pragma unroll
            for (int q = 0; q < 4; ++q) wv[r][q] = w2s[(obase + r) * 65 + c4 + q];
#pragma unroll
        for (int i = 0; i < 5; ++i) {
            const float* mp = &mix2[(nvbase + i) * 65 + c4];
            float m0 = mp[0], m1 = mp[1], m2 = mp[2], m3 = mp[3];
#pragma unroll
            for (int r = 0; r < 4; ++r)
                accs[i][r] += m0 * wv[r][0] + m1 * wv[r][1] + m2 * wv[r][2] + m3 * wv[r][3];
        }
    }

    __hip_bfloat16* a2h = reinterpret_cast<__hip_bfloat16*>(h1);  // [128][34]
    float b2r[4];
#pragma unroll
    for (int r = 0; r < 4; ++r) b2r[r] = b2[obase + r];
    float s[4] = {0, 0, 0, 0}, q2[4] = {0, 0, 0, 0};
#pragma unroll
    for (int i = 0; i < 5; ++i) {
        int nv = nvbase + i;
        if (nv < 34) {
#pragma unroll
            for (int r = 0; r < 4; ++r) {
                float vv = accs[i][r] + b2r[r];
                s[r] += vv; q2[r] += vv * vv;
                a2h[(obase + r) * 34 + nv] = __float2bfloat16(vv);
            }
        }
    }
#pragma unroll
    for (int r = 0; r < 4; ++r) { redS[ng * 128 + obase + r] = s[r]; redQ[ng * 128 + obase + r] = q2[r]; }
    __syncthreads();
    if (tid < 128) {
        float S = 0.f, Q = 0.f;
#pragma unroll
        for (int g = 0; g < 8; ++g) { S += redS[g * 128 + tid]; Q += redQ[g * 128 + tid]; }
        int slot = blockIdx.x & 15;
        atomicAdd(&st[2048 + slot * 128 + tid], S);
        atomicAdd(&st[4096 + slot * 128 + tid], Q);
    }

    // folded conv layout write: z flat index = b*ZBv + oo*8704 + t0*17 + (n*17+v), as uint pairs
    const unsigned int* a2u32 = reinterpret_cast<const unsigned int*>(h1);
    unsigned int* zout = reinterpret_cast<unsigned int*>(zpre);
    size_t base = ((size_t)b * (size_t)ZBv + (size_t)t0 * 17) >> 1;
    for (int e = tid; e < 128 * 17; e += 256) {
        int oo = e / 17, q = e - oo * 17;
        zout[base + (size_t)oo * 4352 + q] = a2u32[oo * 17 + q];
    }
}

// transpose z[b][ci][sf] -> zr[b][sf][ci] with fused BN2+ReLU (per-ci scale/shift)
__global__ __launch_bounds__(256) void k_tr(const __hip_bfloat16* __restrict__ z,
                                            const float* __restrict__ scc,
                                            const float* __restrict__ shc,
                                            __hip_bfloat16* __restrict__ zr) {
    __shared__ __hip_bfloat16 tile[64][72];
    int tid = threadIdx.x;
    int bi = blockIdx.x;
    int b = bi / 272;
    int r = bi - b * 272;
    int ci0 = (r >> 3) * 64;
    int sf0 = (r & 7) * 64;

    const __hip_bfloat16* zb = z + (size_t)b * ZBv;
    for (int e = tid; e < 512; e += 256) {
        int row = e >> 3, c8 = e & 7;
        short8v v = *reinterpret_cast<const short8v*>(zb + (size_t)(ci0 + row) * 512 + sf0 + c8 * 8);
        *reinterpret_cast<short8v*>(&tile[row][c8 * 8]) = v;
    }
    __syncthreads();
    __hip_bfloat16* zrb = zr + (size_t)b * ZBv;
    for (int e = tid; e < 512; e += 256) {
        int sfr = e >> 3, g8 = e & 7;
        int cib = ci0 + g8 * 8;
        short8v rv;
#pragma unroll
        for (int j = 0; j < 8; ++j) {
            float f = __bfloat162float(tile[g8 * 8 + j][sfr]);
            float t = fmaxf(f * scc[cib + j] + shc[cib + j], 0.f);
            __hip_bfloat16 h = __float2bfloat16(t);
            rv[j] = *reinterpret_cast<short*>(&h);
        }
        *reinterpret_cast<short8v*>(zrb + (size_t)(sf0 + sfr) * 2176 + cib) = rv;
    }
}

// MFMA temporal conv over folded axis: out[b][o][sf] = sum_k sum_ci wkt[k][o][ci] * zr[b][sf+k-1][ci]
__global__ __launch_bounds__(256, 3) void k_conv_mfma(const __hip_bfloat16* __restrict__ zr,
                                                      const __hip_bfloat16* __restrict__ wkt,
                                                      const float* __restrict__ bt,
                                                      float* __restrict__ cp,
                                                      float* __restrict__ s3,
                                                      float* __restrict__ ss3) {
    int tid = threadIdx.x;
    int b = blockIdx.x >> 3;
    int s0 = (blockIdx.x & 7) << 6;
    int wid = tid >> 6, lane = tid & 63;
    int l15 = lane & 15, l4 = lane >> 4;
    int m0 = (wid >> 1) * 64;
    int n0 = s0 + (wid & 1) * 32;

    f32x4 acc[4][2];
#pragma unroll
    for (int mi = 0; mi < 4; ++mi)
#pragma unroll
        for (int ni = 0; ni < 2; ++ni) acc[mi][ni] = (f32x4){0.f, 0.f, 0.f, 0.f};

    const __hip_bfloat16* aw = wkt + (size_t)l15 * 2176 + l4 * 8;
    const __hip_bfloat16* zb = zr + (size_t)b * 512 * 2176 + l4 * 8;
    size_t boff[3][2];
    int bok[3][2];
#pragma unroll
    for (int k = 0; k < 3; ++k)
#pragma unroll
        for (int ni = 0; ni < 2; ++ni) {
            int row = n0 + ni * 16 + l15 + k - 1;
            int ok = (unsigned)row < 512u;
            int rowc = ok ? row : 0;
            boff[k][ni] = (size_t)rowc * 2176;
            bok[k][ni] = ok;
        }

    for (int t = 0; t < 68; ++t) {
        int co = t * 32;
        short8v a_[3][4], b_[3][2];
#pragma unroll
        for (int k = 0; k < 3; ++k)
#pragma unroll
            for (int mi = 0; mi < 4; ++mi)
                a_[k][mi] = *reinterpret_cast<const short8v*>(
                    aw + (size_t)(k * 128 + m0 + mi * 16) * 2176 + co);
#pragma unroll
        for (int k = 0; k < 3; ++k)
#pragma unroll
            for (int ni = 0; ni < 2; ++ni) {
                short8v bv = *reinterpret_cast<const short8v*>(zb + boff[k][ni] + co);
                if (!bok[k][ni]) bv = (short8v)0;
                b_[k][ni] = bv;
            }
#pragma unroll
        for (int k = 0; k < 3; ++k)
#pragma unroll
            for (int mi = 0; mi < 4; ++mi)
#pragma unroll
                for (int ni = 0; ni < 2; ++ni)
                    acc[mi][ni] = __builtin_amdgcn_mfma_f32_16x16x32_bf16(
                        a_[k][mi], b_[k][ni], acc[mi][ni], 0, 0, 0);
    }

    int slot = blockIdx.x & 15;
#pragma unroll
    for (int mi = 0; mi < 4; ++mi)
#pragma unroll
        for (int r = 0; r < 4; ++r) {
            int o = m0 + mi * 16 + l4 * 4 + r;
            float btv = bt[o];
            float v0 = acc[mi][0][r] + btv;
            float v1 = acc[mi][1][r] + btv;
            size_t cb = ((size_t)(b * 128 + o)) * 512 + n0 + l15;
            cp[cb] = v0;
            cp[cb + 16] = v1;
            float sv = v0 + v1;
            float sq = v0 * v0 + v1 * v1;
#pragma unroll
            for (int off = 1; off < 16; off <<= 1) {
                sv += __shfl_xor(sv, off, 64);
                sq += __shfl_xor(sq, off, 64);
            }
            if (l15 == 0) {
                atomicAdd(&s3[slot * 128 + o], sv);
                atomicAdd(&ss3[slot * 128 + o], sq);
            }
        }
}

// fallback fp32 conv (round-0, proven correct)
__global__ __launch_bounds__(256) void k_conv(const __hip_bfloat16* __restrict__ zpre,
                                              const float* __restrict__ wt_t,
                                              const float* __restrict__ bt,
                                              const float* __restrict__ sc2,
                                              const float* __restrict__ sh2,
                                              float* __restrict__ cp,
                                              float* __restrict__ s3,
                                              float* __restrict__ ss3) {
    __shared__ float zt[16 * 68];
    __shared__ float wtt[48 * 128];
    int tid = threadIdx.x;
    int b = blockIdx.x >> 3;
    int s0 = (blockIdx.x & 7) * 64;
    int o = tid & 127, sh = tid >> 7;
    float acc[32];
#pragma unroll
    for (int j = 0; j < 32; ++j) acc[j] = 0.f;
    const size_t zbase = (size_t)b * (size_t)ZBv;

    for (int c0 = 0; c0 < 2176; c0 += 16) {
        __syncthreads();
        for (int e = tid; e < 16 * 66; e += 256) {
            int cc = e / 66, ss = e - cc * 66;
            int c = c0 + cc;
            int sAbs = s0 - 1 + ss;
            float v = 0.f;
            if (sAbs >= 0 && sAbs < 512) {
                float raw = __bfloat162float(zpre[zbase + (size_t)c * 512 + sAbs]);
                int hch = c / 17;
                float t = raw * sc2[hch] + sh2[hch];
                v = fmaxf(t, 0.f);
            }
            zt[cc * 68 + ss] = v;
        }
        {
            const float4* ws4 = reinterpret_cast<const float4*>(wt_t + (size_t)c0 * 3 * 128);
            float4* wtt4 = reinterpret_cast<float4*>(wtt);
            for (int e = tid; e < 1536; e += 256) wtt4[e] = ws4[e];
        }
        __syncthreads();
#pragma unroll 2
        for (int cc = 0; cc < 16; ++cc) {
            float zrg[36];
            const float4* zp = reinterpret_cast<const float4*>(&zt[cc * 68 + sh * 32]);
#pragma unroll
            for (int q = 0; q < 9; ++q) {
                float4 f = zp[q];
                zrg[4 * q] = f.x; zrg[4 * q + 1] = f.y; zrg[4 * q + 2] = f.z; zrg[4 * q + 3] = f.w;
            }
            float w0 = wtt[(cc * 3 + 0) * 128 + o];
            float w1v = wtt[(cc * 3 + 1) * 128 + o];
            float w2v = wtt[(cc * 3 + 2) * 128 + o];
#pragma unroll
            for (int j = 0; j < 32; ++j)
                acc[j] += w0 * zrg[j] + w1v * zrg[j + 1] + w2v * zrg[j + 2];
        }
    }
    float bb = bt[o];
    float s = 0.f, s2 = 0.f;
    float* cpp = cp + ((size_t)b * 128 + o) * 512 + s0 + sh * 32;
#pragma unroll
    for (int j = 0; j < 32; ++j) {
        float v = acc[j] + bb;
        s += v; s2 += v * v;
        acc[j] = v;
    }
    float4* cp4 = reinterpret_cast<float4*>(cpp);
#pragma unroll
    for (int q = 0; q < 8; ++q) cp4[q] = make_float4(acc[4 * q], acc[4 * q + 1], acc[4 * q + 2], acc[4 * q + 3]);
    int slot = blockIdx.x & 15;
    atomicAdd(&s3[slot * 128 + o], s);
    atomicAdd(&ss3[slot * 128 + o], s2);
}

__global__ __launch_bounds__(256) void k_out(const float* __restrict__ cp,
                                             const float* __restrict__ sc3,
                                             const float* __restrict__ sh3,
                                             float* __restrict__ out) {
    __shared__ float tile[128 * 33];
    int tid = threadIdx.x;
    int b = blockIdx.x >> 4;
    int t0 = (blockIdx.x & 15) * 32;
    for (int e = tid; e < 128 * 32; e += 256) {
        int o = e >> 5, tj = e & 31;
        tile[o * 33 + tj] = cp[((size_t)b * 128 + o) * 512 + t0 + tj];
    }
    __syncthreads();
    for (int e = tid; e < 128 * 32; e += 256) {
        int o = e & 127, th = e >> 7;
        float v = tile[o * 33 + th] * sc3[o] + sh3[o];
        out[((size_t)b * 512 + t0 + th) * 128 + o] = fmaxf(v, 0.f);
    }
}

extern "C" void kernel_launch(void* const* d_in, const int* in_sizes, int n_in,
                              void* d_out, int out_size, void* d_ws, size_t ws_size,
                              hipStream_t stream) {
    const float* x   = (const float*)d_in[0];
    const float* adj = (const float*)d_in[1];
    const float* w1  = (const float*)d_in[2];
    const float* b1  = (const float*)d_in[3];
    const float* g1  = (const float*)d_in[4];
    const float* be1 = (const float*)d_in[5];
    const float* w2  = (const float*)d_in[6];
    const float* b2  = (const float*)d_in[7];
    const float* g2  = (const float*)d_in[8];
    const float* be2 = (const float*)d_in[9];
    const float* wt  = (const float*)d_in[10];
    const float* bt  = (const float*)d_in[11];
    const float* gt  = (const float*)d_in[12];
    const float* bet = (const float*)d_in[13];
    float* out = (float*)d_out;

    char* ws = (char*)d_ws;
    bool big = ws_size >= NEED_P;

    __hip_bfloat16* zpre = (__hip_bfloat16*)(ws + OFF_Z);
    float* st = (float*)(ws + (big ? OFF_STP : OFF_STF));

    hipMemsetAsync(st, 0, 10240 * sizeof(float), stream);

    k_stats1<<<dim3(1024), dim3(256), 0, stream>>>(x, adj, w1, b1, st);
    k_finalize<<<dim3(1), dim3(128), 0, stream>>>(st, st + 1024, g1, be1,
                                                  st + 10240, st + 10304, 64, 1.f / 557056.f);
    k_gcn<<<dim3(16384), dim3(256), 0, stream>>>(x, adj, w1, b1,
                                                 st + 10240, st + 10304,
                                                 w2, b2, st, zpre);
    k_finalize<<<dim3(1), dim3(128), 0, stream>>>(st + 2048, st + 4096, g2, be2,
                                                  st + 10368, st + 10496, 128, 1.f / 557056.f);

    if (big) {
        __hip_bfloat16* zr  = (__hip_bfloat16*)(ws + OFF_ZR);
        __hip_bfloat16* wkt = (__hip_bfloat16*)(ws + OFF_WKT);
        float* cp = (float*)(ws + OFF_Z);   // alias z (dead after k_tr)
        k_wt_bf16<<<dim3(3264), dim3(256), 0, stream>>>(wt, wkt);
        k_expand<<<dim3(9), dim3(256), 0, stream>>>(st + 10368, st + 10496,
                                                    st + 10880, st + 13056);
        k_tr<<<dim3(17408), dim3(256), 0, stream>>>(zpre, st + 10880, st + 13056, zr);
        k_conv_mfma<<<dim3(512), dim3(256), 0, stream>>>(zr, wkt, bt,
                                                         cp, st + 6144, st + 8192);
        k_finalize<<<dim3(1), dim3(128), 0, stream>>>(st + 6144, st + 8192, gt, bet,
                                                      st + 10624, st + 10752, 128, 1.f / 32768.f);
        k_out<<<dim3(1024), dim3(256), 0, stream>>>(cp, st + 10624, st + 10752, out);
    } else {
        float* wt_t = (float*)(ws + OFF_WTF);
        float* cp   = (float*)(ws + OFF_CPF);
        k_wt_transpose<<<dim3((6528 * 128 + 255) / 256), dim3(256), 0, stream>>>(wt, wt_t);
        k_conv<<<dim3(512), dim3(256), 0, stream>>>(zpre, wt_t, bt,
                                                    st + 10368, st + 10496,
                                                    cp, st + 6144, st + 8192);
        k_finalize<<<dim3(1), dim3(128), 0, stream>>>(st + 6144, st + 8192, gt, bet,
                                                      st + 10624, st + 10752, 128, 1.f / 32768.f);
        k_out<<<dim3(1024), dim3(256), 0, stream>>>(cp, st + 10624, st + 10752, out);
    }
}

// Round 4
// 807.496 us; speedup vs baseline: 2.1911x; 2.1911x over previous
//
#include <hip/hip_runtime.h>
#include <hip/hip_bf16.h>

#define EPS 1e-5f

static constexpr int Bv = 64, Tv = 512, Vv = 17, Hv = 128;
static constexpr int CHv = Hv * Vv;                // 2176
static constexpr long ZBv = (long)CHv * Tv;        // 1114112 elems per batch

typedef __attribute__((ext_vector_type(8))) short short8v;
typedef __attribute__((ext_vector_type(4))) float f32x4;

// ---- workspace layout (fits in round-0-proven ~163MB budget) ----
static constexpr size_t SZ_Z    = (size_t)Bv * (size_t)ZBv * 2;      // 142,606,336
static constexpr size_t OFF_ZR  = 0;                                  // zr [b][sf][ci] bf16 (pre-BN2, then in-place BN2+relu)
static constexpr size_t OFF_WKT = OFF_ZR + SZ_Z;                      // bf16 [k][o][ci]
static constexpr size_t SZ_WKT  = (size_t)3 * 128 * 2176 * 2;        // 1,671,168
static constexpr size_t OFF_CP  = OFF_WKT + SZ_WKT;                   // f32 conv out [b][o][sf]
static constexpr size_t SZ_CP   = (size_t)Bv * Hv * Tv * 4;          // 16,777,216
static constexpr size_t OFF_ST  = OFF_CP + SZ_CP;                     // stats floats
// stats region (floats):
//  0:s1sp[1024] 1024:ss1sp 2048:s2sp[2048] 4096:ss2sp 6144:s3sp[2048] 8192:ss3sp
//  10240:sc1[64] 10304:sh1[64] 10368:sc2[128] 10496:sh2[128] 10624:sc3[128] 10752:sh3[128]
//  10880:scc[2176] 13056:shc[2176]   (end 15232)

__global__ __launch_bounds__(256) void k_wt_bf16(const float* __restrict__ wt,
                                                 __hip_bfloat16* __restrict__ wkt) {
    int e = blockIdx.x * 256 + threadIdx.x;   // e = (k*128+o)*2176 + c
    if (e >= 3 * 128 * 2176) return;
    int c = e % 2176;
    int ko = e / 2176;
    int o = ko % 128, k = ko / 128;
    wkt[e] = __float2bfloat16(wt[(size_t)o * 6528 + c * 3 + k]);
}

__global__ __launch_bounds__(256) void k_stats1(const float* __restrict__ x,
                                                const float* __restrict__ adj,
                                                const float* __restrict__ w1,
                                                const float* __restrict__ b1,
                                                float* __restrict__ st) {
    __shared__ float adj_s[289];
    __shared__ float xs[32 * 34];
    __shared__ float mix[32 * 34];
    __shared__ float red[256], red2[256];
    int tid = threadIdx.x;
    int n0 = blockIdx.x * 32;
    for (int i = tid; i < 289; i += 256) adj_s[i] = adj[i];
    for (int i = tid; i < 1088; i += 256) xs[i] = x[(size_t)n0 * 34 + i];
    __syncthreads();
    for (int e = tid; e < 1088; e += 256) {
        int n = e / 34, r = e % 34;
        int w = r >> 1, c = r & 1;
        float acc = 0.f;
        for (int v = 0; v < 17; ++v) acc += xs[n * 34 + v * 2 + c] * adj_s[v * 17 + w];
        mix[n * 34 + w * 2 + c] = acc;
    }
    __syncthreads();
    int o = tid & 63, g = tid >> 6;
    float w0 = w1[o * 2], w1v = w1[o * 2 + 1], bb = b1[o];
    float s = 0.f, s2 = 0.f;
    for (int n = g; n < 32; n += 4)
        for (int v = 0; v < 17; ++v) {
            float a = mix[n * 34 + v * 2] * w0 + mix[n * 34 + v * 2 + 1] * w1v + bb;
            s += a; s2 += a * a;
        }
    red[tid] = s; red2[tid] = s2;
    __syncthreads();
    if (tid < 64) {
        float S  = red[tid] + red[tid + 64] + red[tid + 128] + red[tid + 192];
        float S2 = red2[tid] + red2[tid + 64] + red2[tid + 128] + red2[tid + 192];
        int slot = blockIdx.x & 15;
        atomicAdd(&st[slot * 64 + o], S);
        atomicAdd(&st[1024 + slot * 64 + o], S2);
    }
}

__global__ void k_finalize(const float* __restrict__ sums, const float* __restrict__ sumsq,
                           const float* __restrict__ gamma, const float* __restrict__ beta,
                           float* __restrict__ scale, float* __restrict__ shift,
                           int count, float inv_denom) {
    int o = threadIdx.x;
    if (o >= count) return;
    float S = 0.f, Q = 0.f;
    for (int j = 0; j < 16; ++j) { S += sums[j * count + o]; Q += sumsq[j * count + o]; }
    float m = S * inv_denom;
    float var = Q * inv_denom - m * m;
    float rstd = rsqrtf(var + EPS);
    float sc = rstd * gamma[o];
    scale[o] = sc;
    shift[o] = beta[o] - m * sc;
}

__global__ __launch_bounds__(256) void k_expand(const float* __restrict__ sc2,
                                                const float* __restrict__ sh2,
                                                float* __restrict__ scc,
                                                float* __restrict__ shc) {
    int i = blockIdx.x * 256 + threadIdx.x;
    if (i >= 2176) return;
    int h = i / 17;
    scc[i] = sc2[h];
    shc[i] = sh2[h];
}

// processes one (b, pair of t). Writes pre-BN2 block-2 output DIRECTLY in the
// folded-transposed conv layout zr[b][sf][ci]:
//   flat-within-batch idx = o*8704 + t*17 + v ; ci = idx/512 = o*17 + (t*17+v)/512 ;
//   sf = idx%512 = (t*17+v)%512   (8704 = 17*512, so o does not affect sf)
__global__ __launch_bounds__(256) void k_gcn(const float* __restrict__ x,
                                             const float* __restrict__ adj,
                                             const float* __restrict__ w1,
                                             const float* __restrict__ b1,
                                             const float* __restrict__ sc1,
                                             const float* __restrict__ sh1,
                                             const float* __restrict__ w2,
                                             const float* __restrict__ b2,
                                             float* __restrict__ st,
                                             __hip_bfloat16* __restrict__ zr) {
    __shared__ float adj_s[289];
    __shared__ float xs[68];
    __shared__ float mix1[68];
    __shared__ float h1[34 * 65];    // [nv][c] padded; later aliased as bf16 a2[128][34]
    __shared__ float mix2[40 * 65];  // [nv][c] padded (rows 34..39 zero)
    __shared__ float w2s[128 * 65];  // [o][c] padded
    __shared__ float redS[8 * 128], redQ[8 * 128];

    int tid = threadIdx.x;
    int b = blockIdx.x >> 8;
    int t0 = (blockIdx.x & 255) * 2;

    for (int i = tid; i < 289; i += 256) adj_s[i] = adj[i];
    for (int i = tid; i < 68; i += 256) xs[i] = x[(size_t)(b * 512 + t0) * 34 + i];
    for (int i = tid; i < 8192; i += 256) { int o = i >> 6, c = i & 63; w2s[o * 65 + c] = w2[i]; }
    __syncthreads();

    for (int e = tid; e < 68; e += 256) {
        int n = e / 34, r = e % 34, w = r >> 1, c = r & 1;
        float acc = 0.f;
        for (int v = 0; v < 17; ++v) acc += xs[n * 34 + v * 2 + c] * adj_s[v * 17 + w];
        mix1[n * 34 + w * 2 + c] = acc;
    }
    __syncthreads();

    for (int e = tid; e < 34 * 64; e += 256) {
        int nv = e >> 6, o = e & 63;
        int n = nv / 17, v = nv - n * 17;
        float a = mix1[n * 34 + v * 2] * w1[o * 2] + mix1[n * 34 + v * 2 + 1] * w1[o * 2 + 1] + b1[o];
        a = a * sc1[o] + sh1[o];
        h1[nv * 65 + o] = fmaxf(a, 0.f);
    }
    __syncthreads();

    for (int e = tid; e < 136; e += 256) {
        int nw = e >> 2, cq = (e & 3) << 4;
        int n = nw / 17, w = nw - n * 17;
        float a[16];
#pragma unroll
        for (int i = 0; i < 16; ++i) a[i] = 0.f;
        for (int v = 0; v < 17; ++v) {
            float ad = adj_s[v * 17 + w];
            const float* hp = &h1[(n * 17 + v) * 65 + cq];
#pragma unroll
            for (int i = 0; i < 16; ++i) a[i] += ad * hp[i];
        }
        float* mp = &mix2[nw * 65 + cq];
#pragma unroll
        for (int i = 0; i < 16; ++i) mp[i] = a[i];
    }
    for (int e = tid; e < 6 * 65; e += 256) mix2[34 * 65 + e] = 0.f;
    __syncthreads();

    int og = tid & 31, ng = tid >> 5;
    int obase = og << 2, nvbase = ng * 5;
    float accs[5][4];
#pragma unroll
    for (int i = 0; i < 5; ++i)
#pragma unroll
        for (int r = 0; r < 4; ++r) accs[i][r] = 0.f;
    for (int c4 = 0; c4 < 64; c4 += 4) {
        float wv[4][4];
#pragma unroll
        for (int r = 0; r < 4; ++r)
#pragma unroll
            for (int q = 0; q < 4; ++q) wv[r][q] = w2s[(obase + r) * 65 + c4 + q];
#pragma unroll
        for (int i = 0; i < 5; ++i) {
            const float* mp = &mix2[(nvbase + i) * 65 + c4];
            float m0 = mp[0], m1 = mp[1], m2 = mp[2], m3 = mp[3];
#pragma unroll
            for (int r = 0; r < 4; ++r)
                accs[i][r] += m0 * wv[r][0] + m1 * wv[r][1] + m2 * wv[r][2] + m3 * wv[r][3];
        }
    }

    __hip_bfloat16* a2h = reinterpret_cast<__hip_bfloat16*>(h1);  // [128 o][34 nv] bf16 (8704 B)
    float b2r[4];
#pragma unroll
    for (int r = 0; r < 4; ++r) b2r[r] = b2[obase + r];
    float s[4] = {0, 0, 0, 0}, q2[4] = {0, 0, 0, 0};
#pragma unroll
    for (int i = 0; i < 5; ++i) {
        int nv = nvbase + i;
        if (nv < 34) {
#pragma unroll
            for (int r = 0; r < 4; ++r) {
                float vv = accs[i][r] + b2r[r];
                s[r] += vv; q2[r] += vv * vv;
                a2h[(obase + r) * 34 + nv] = __float2bfloat16(vv);
            }
        }
    }
#pragma unroll
    for (int r = 0; r < 4; ++r) { redS[ng * 128 + obase + r] = s[r]; redQ[ng * 128 + obase + r] = q2[r]; }
    __syncthreads();
    if (tid < 128) {
        float S = 0.f, Q = 0.f;
#pragma unroll
        for (int g = 0; g < 8; ++g) { S += redS[g * 128 + tid]; Q += redQ[g * 128 + tid]; }
        int slot = blockIdx.x & 15;
        atomicAdd(&st[2048 + slot * 128 + tid], S);
        atomicAdd(&st[4096 + slot * 128 + tid], Q);
    }

    // scattered write into zr[b][sf][ci]
    __hip_bfloat16* zrb = zr + (size_t)b * (size_t)ZBv;
    int base_tv = t0 * 17;
    for (int e = tid; e < 4352; e += 256) {   // e = oo*34 + j
        int oo = e / 34, j = e - oo * 34;
        int tv = base_tv + j;                  // < 8704
        int sf = tv & 511;
        int q  = tv >> 9;
        zrb[(size_t)sf * 2176 + oo * 17 + q] = a2h[e];
    }
}

// in-place BN2 + ReLU on zr (bf16), rows of 2176 (per-ci scale/shift)
__global__ __launch_bounds__(256) void k_bn2(__hip_bfloat16* __restrict__ z,
                                             const float* __restrict__ scc,
                                             const float* __restrict__ shc) {
    size_t base = (size_t)blockIdx.x * 2176;
    for (int g = threadIdx.x; g < 272; g += 256) {
        int c = g * 8;
        short8v v = *reinterpret_cast<const short8v*>(z + base + c);
        short8v r;
#pragma unroll
        for (int j = 0; j < 8; ++j) {
            unsigned u = ((unsigned)(unsigned short)v[j]) << 16;
            float f = __uint_as_float(u);
            float t = fmaxf(f * scc[c + j] + shc[c + j], 0.f);
            __hip_bfloat16 h = __float2bfloat16(t);
            r[j] = *reinterpret_cast<short*>(&h);
        }
        *reinterpret_cast<short8v*>(z + base + c) = r;
    }
}

// MFMA temporal conv over folded axis: out[b][o][sf] = sum_k sum_ci wkt[k][o][ci] * zr[b][sf+k-1][ci]
// block: 128 o x 64 sf, 4 waves (2x2), wave tile 64 o x 32 sf
__global__ __launch_bounds__(256, 3) void k_conv_mfma(const __hip_bfloat16* __restrict__ zr,
                                                      const __hip_bfloat16* __restrict__ wkt,
                                                      const float* __restrict__ bt,
                                                      float* __restrict__ cp,
                                                      float* __restrict__ s3,
                                                      float* __restrict__ ss3) {
    int tid = threadIdx.x;
    int b = blockIdx.x >> 3;
    int s0 = (blockIdx.x & 7) << 6;
    int wid = tid >> 6, lane = tid & 63;
    int l15 = lane & 15, l4 = lane >> 4;
    int m0 = (wid >> 1) * 64;
    int n0 = s0 + (wid & 1) * 32;

    f32x4 acc[4][2];
#pragma unroll
    for (int mi = 0; mi < 4; ++mi)
#pragma unroll
        for (int ni = 0; ni < 2; ++ni) acc[mi][ni] = (f32x4){0.f, 0.f, 0.f, 0.f};

    const __hip_bfloat16* aw = wkt + (size_t)l15 * 2176 + l4 * 8;
    const __hip_bfloat16* zb = zr + (size_t)b * 512 * 2176 + l4 * 8;
    size_t boff[3][2];
    int bok[3][2];
#pragma unroll
    for (int k = 0; k < 3; ++k)
#pragma unroll
        for (int ni = 0; ni < 2; ++ni) {
            int row = n0 + ni * 16 + l15 + k - 1;
            int ok = (unsigned)row < 512u;
            int rowc = ok ? row : 0;
            boff[k][ni] = (size_t)rowc * 2176;
            bok[k][ni] = ok;
        }

    for (int t = 0; t < 68; ++t) {
        int co = t * 32;
        short8v a_[3][4], b_[3][2];
#pragma unroll
        for (int k = 0; k < 3; ++k)
#pragma unroll
            for (int mi = 0; mi < 4; ++mi)
                a_[k][mi] = *reinterpret_cast<const short8v*>(
                    aw + (size_t)(k * 128 + m0 + mi * 16) * 2176 + co);
#pragma unroll
        for (int k = 0; k < 3; ++k)
#pragma unroll
            for (int ni = 0; ni < 2; ++ni) {
                short8v bv = *reinterpret_cast<const short8v*>(zb + boff[k][ni] + co);
                if (!bok[k][ni]) bv = (short8v)0;
                b_[k][ni] = bv;
            }
#pragma unroll
        for (int k = 0; k < 3; ++k)
#pragma unroll
            for (int mi = 0; mi < 4; ++mi)
#pragma unroll
                for (int ni = 0; ni < 2; ++ni)
                    acc[mi][ni] = __builtin_amdgcn_mfma_f32_16x16x32_bf16(
                        a_[k][mi], b_[k][ni], acc[mi][ni], 0, 0, 0);
    }

    int slot = blockIdx.x & 15;
#pragma unroll
    for (int mi = 0; mi < 4; ++mi)
#pragma unroll
        for (int r = 0; r < 4; ++r) {
            int o = m0 + mi * 16 + l4 * 4 + r;
            float btv = bt[o];
            float v0 = acc[mi][0][r] + btv;
            float v1 = acc[mi][1][r] + btv;
            size_t cb = ((size_t)(b * 128 + o)) * 512 + n0 + l15;
            cp[cb] = v0;
            cp[cb + 16] = v1;
            float sv = v0 + v1;
            float sq = v0 * v0 + v1 * v1;
#pragma unroll
            for (int off = 1; off < 16; off <<= 1) {
                sv += __shfl_xor(sv, off, 64);
                sq += __shfl_xor(sq, off, 64);
            }
            if (l15 == 0) {
                atomicAdd(&s3[slot * 128 + o], sv);
                atomicAdd(&ss3[slot * 128 + o], sq);
            }
        }
}

__global__ __launch_bounds__(256) void k_out(const float* __restrict__ cp,
                                             const float* __restrict__ sc3,
                                             const float* __restrict__ sh3,
                                             float* __restrict__ out) {
    __shared__ float tile[128 * 33];
    int tid = threadIdx.x;
    int b = blockIdx.x >> 4;
    int t0 = (blockIdx.x & 15) * 32;
    for (int e = tid; e < 128 * 32; e += 256) {
        int o = e >> 5, tj = e & 31;
        tile[o * 33 + tj] = cp[((size_t)b * 128 + o) * 512 + t0 + tj];
    }
    __syncthreads();
    for (int e = tid; e < 128 * 32; e += 256) {
        int o = e & 127, th = e >> 7;
        float v = tile[o * 33 + th] * sc3[o] + sh3[o];
        out[((size_t)b * 512 + t0 + th) * 128 + o] = fmaxf(v, 0.f);
    }
}

extern "C" void kernel_launch(void* const* d_in, const int* in_sizes, int n_in,
                              void* d_out, int out_size, void* d_ws, size_t ws_size,
                              hipStream_t stream) {
    const float* x   = (const float*)d_in[0];
    const float* adj = (const float*)d_in[1];
    const float* w1  = (const float*)d_in[2];
    const float* b1  = (const float*)d_in[3];
    const float* g1  = (const float*)d_in[4];
    const float* be1 = (const float*)d_in[5];
    const float* w2  = (const float*)d_in[6];
    const float* b2  = (const float*)d_in[7];
    const float* g2  = (const float*)d_in[8];
    const float* be2 = (const float*)d_in[9];
    const float* wt  = (const float*)d_in[10];
    const float* bt  = (const float*)d_in[11];
    const float* gt  = (const float*)d_in[12];
    const float* bet = (const float*)d_in[13];
    float* out = (float*)d_out;

    char* ws = (char*)d_ws;
    __hip_bfloat16* zr  = (__hip_bfloat16*)(ws + OFF_ZR);
    __hip_bfloat16* wkt = (__hip_bfloat16*)(ws + OFF_WKT);
    float* cp = (float*)(ws + OFF_CP);
    float* st = (float*)(ws + OFF_ST);

    hipMemsetAsync(st, 0, 10240 * sizeof(float), stream);

    k_wt_bf16<<<dim3(3264), dim3(256), 0, stream>>>(wt, wkt);
    k_stats1<<<dim3(1024), dim3(256), 0, stream>>>(x, adj, w1, b1, st);
    k_finalize<<<dim3(1), dim3(128), 0, stream>>>(st, st + 1024, g1, be1,
                                                  st + 10240, st + 10304, 64, 1.f / 557056.f);
    k_gcn<<<dim3(16384), dim3(256), 0, stream>>>(x, adj, w1, b1,
                                                 st + 10240, st + 10304,
                                                 w2, b2, st, zr);
    k_finalize<<<dim3(1), dim3(128), 0, stream>>>(st + 2048, st + 4096, g2, be2,
                                                  st + 10368, st + 10496, 128, 1.f / 557056.f);
    k_expand<<<dim3(9), dim3(256), 0, stream>>>(st + 10368, st + 10496,
                                                st + 10880, st + 13056);
    k_bn2<<<dim3(32768), dim3(256), 0, stream>>>(zr, st + 10880, st + 13056);
    k_conv_mfma<<<dim3(512), dim3(256), 0, stream>>>(zr, wkt, bt,
                                                     cp, st + 6144, st + 8192);
    k_finalize<<<dim3(1), dim3(128), 0, stream>>>(st + 6144, st + 8192, gt, bet,
                                                  st + 10624, st + 10752, 128, 1.f / 32768.f);
    k_out<<<dim3(1024), dim3(256), 0, stream>>>(cp, st + 10624, st + 10752, out);
}

// Round 5
// 695.757 us; speedup vs baseline: 2.5430x; 1.1606x over previous
//
#include <hip/hip_runtime.h>
#include <hip/hip_bf16.h>

#define EPS 1e-5f

static constexpr int Bv = 64, Tv = 512, Vv = 17, Hv = 128;
static constexpr int CHv = Hv * Vv;                // 2176
static constexpr long ZBv = (long)CHv * Tv;        // 1114112 elems per batch

typedef __attribute__((ext_vector_type(8))) short short8v;
typedef __attribute__((ext_vector_type(4))) float f32x4;

// ---- workspace layout (~161 MB, fits proven budget) ----
// Channel axis PERMUTED: ci' = q*128 + o  (orig ci = o*17 + q). Conv sums over
// ci in any order as long as weights use the same permutation.
static constexpr size_t SZ_Z    = (size_t)Bv * (size_t)ZBv * 2;      // 142,606,336
static constexpr size_t OFF_ZR  = 0;                                  // zr [b][sf][ci'] bf16
static constexpr size_t OFF_WKT = OFF_ZR + SZ_Z;                      // bf16 [k][o_out][ci']
static constexpr size_t SZ_WKT  = (size_t)3 * 128 * 2176 * 2;        // 1,671,168
static constexpr size_t OFF_CP  = OFF_WKT + SZ_WKT;                   // f32 conv out [b][o][sf]
static constexpr size_t SZ_CP   = (size_t)Bv * Hv * Tv * 4;          // 16,777,216
static constexpr size_t OFF_ST  = OFF_CP + SZ_CP;
// stats floats:
//  0:s1sp[1024] 1024:ss1sp 2048:s2sp[2048] 4096:ss2sp 6144:s3sp[2048] 8192:ss3sp
//  10240:sc1[64] 10304:sh1[64] 10368:sc2[128] 10496:sh2[128] 10624:sc3[128] 10752:sh3[128]

__global__ __launch_bounds__(256) void k_wt_bf16(const float* __restrict__ wt,
                                                 __hip_bfloat16* __restrict__ wkt) {
    int e = blockIdx.x * 256 + threadIdx.x;   // e = (k*128+o_out)*2176 + ci'
    if (e >= 3 * 128 * 2176) return;
    int cip = e % 2176;
    int ko = e / 2176;
    int o_out = ko % 128, k = ko / 128;
    int q = cip >> 7, o_in = cip & 127;        // ci' = q*128 + o_in
    int orig_ck = (o_in * 17 + q) * 3 + k;     // orig ci = o_in*17+q, then *3+k
    wkt[e] = __float2bfloat16(wt[(size_t)o_out * 6528 + orig_ck]);
}

__global__ __launch_bounds__(256) void k_stats1(const float* __restrict__ x,
                                                const float* __restrict__ adj,
                                                const float* __restrict__ w1,
                                                const float* __restrict__ b1,
                                                float* __restrict__ st) {
    __shared__ float adj_s[289];
    __shared__ float xs[32 * 34];
    __shared__ float mix[32 * 34];
    __shared__ float red[256], red2[256];
    int tid = threadIdx.x;
    int n0 = blockIdx.x * 32;
    for (int i = tid; i < 289; i += 256) adj_s[i] = adj[i];
    for (int i = tid; i < 1088; i += 256) xs[i] = x[(size_t)n0 * 34 + i];
    __syncthreads();
    for (int e = tid; e < 1088; e += 256) {
        int n = e / 34, r = e % 34;
        int w = r >> 1, c = r & 1;
        float acc = 0.f;
        for (int v = 0; v < 17; ++v) acc += xs[n * 34 + v * 2 + c] * adj_s[v * 17 + w];
        mix[n * 34 + w * 2 + c] = acc;
    }
    __syncthreads();
    int o = tid & 63, g = tid >> 6;
    float w0 = w1[o * 2], w1v = w1[o * 2 + 1], bb = b1[o];
    float s = 0.f, s2 = 0.f;
    for (int n = g; n < 32; n += 4)
        for (int v = 0; v < 17; ++v) {
            float a = mix[n * 34 + v * 2] * w0 + mix[n * 34 + v * 2 + 1] * w1v + bb;
            s += a; s2 += a * a;
        }
    red[tid] = s; red2[tid] = s2;
    __syncthreads();
    if (tid < 64) {
        float S  = red[tid] + red[tid + 64] + red[tid + 128] + red[tid + 192];
        float S2 = red2[tid] + red2[tid + 64] + red2[tid + 128] + red2[tid + 192];
        int slot = blockIdx.x & 15;
        atomicAdd(&st[slot * 64 + o], S);
        atomicAdd(&st[1024 + slot * 64 + o], S2);
    }
}

__global__ void k_finalize(const float* __restrict__ sums, const float* __restrict__ sumsq,
                           const float* __restrict__ gamma, const float* __restrict__ beta,
                           float* __restrict__ scale, float* __restrict__ shift,
                           int count, float inv_denom) {
    int o = threadIdx.x;
    if (o >= count) return;
    float S = 0.f, Q = 0.f;
    for (int j = 0; j < 16; ++j) { S += sums[j * count + o]; Q += sumsq[j * count + o]; }
    float m = S * inv_denom;
    float var = Q * inv_denom - m * m;
    float rstd = rsqrtf(var + EPS);
    float sc = rstd * gamma[o];
    scale[o] = sc;
    shift[o] = beta[o] - m * sc;
}

// processes one (b, pair of t). Writes pre-BN2 block-2 output directly into the
// permuted folded conv layout zr[b][sf][ci'], ci' = q*128 + o:
//   tv = t*17+v ; sf = tv & 511 ; q = tv >> 9
// For fixed tv, the 128 o-values are CONTIGUOUS (256 B) at zr[sf][q*128].
__global__ __launch_bounds__(256) void k_gcn(const float* __restrict__ x,
                                             const float* __restrict__ adj,
                                             const float* __restrict__ w1,
                                             const float* __restrict__ b1,
                                             const float* __restrict__ sc1,
                                             const float* __restrict__ sh1,
                                             const float* __restrict__ w2,
                                             const float* __restrict__ b2,
                                             float* __restrict__ st,
                                             __hip_bfloat16* __restrict__ zr) {
    __shared__ float adj_s[289];
    __shared__ float xs[68];
    __shared__ float mix1[68];
    __shared__ __align__(16) float h1[34 * 65];   // [nv][c] padded; later aliased bf16 a2[34][128]
    __shared__ float mix2[40 * 65];               // [nv][c] padded (rows 34..39 zero)
    __shared__ float w2s[64 * 129];               // [c][o] stride 129 (bank-conflict-free)
    __shared__ float redS[8 * 128], redQ[8 * 128];

    int tid = threadIdx.x;
    int b = blockIdx.x >> 8;
    int t0 = (blockIdx.x & 255) * 2;

    for (int i = tid; i < 289; i += 256) adj_s[i] = adj[i];
    for (int i = tid; i < 68; i += 256) xs[i] = x[(size_t)(b * 512 + t0) * 34 + i];
    for (int i = tid; i < 8192; i += 256) {
        float v = w2[i];                          // coalesced read: i = o*64 + c
        int o = i >> 6, c = i & 63;
        w2s[c * 129 + o] = v;                     // bank = (c + o) % 32 -> stride-1, free
    }
    __syncthreads();

    for (int e = tid; e < 68; e += 256) {
        int n = e / 34, r = e % 34, w = r >> 1, c = r & 1;
        float acc = 0.f;
        for (int v = 0; v < 17; ++v) acc += xs[n * 34 + v * 2 + c] * adj_s[v * 17 + w];
        mix1[n * 34 + w * 2 + c] = acc;
    }
    __syncthreads();

    for (int e = tid; e < 34 * 64; e += 256) {
        int nv = e >> 6, o = e & 63;
        int n = nv / 17, v = nv - n * 17;
        float a = mix1[n * 34 + v * 2] * w1[o * 2] + mix1[n * 34 + v * 2 + 1] * w1[o * 2 + 1] + b1[o];
        a = a * sc1[o] + sh1[o];
        h1[nv * 65 + o] = fmaxf(a, 0.f);
    }
    __syncthreads();

    for (int e = tid; e < 136; e += 256) {
        int nw = e >> 2, cq = (e & 3) << 4;
        int n = nw / 17, w = nw - n * 17;
        float a[16];
#pragma unroll
        for (int i = 0; i < 16; ++i) a[i] = 0.f;
        for (int v = 0; v < 17; ++v) {
            float ad = adj_s[v * 17 + w];
            const float* hp = &h1[(n * 17 + v) * 65 + cq];
#pragma unroll
            for (int i = 0; i < 16; ++i) a[i] += ad * hp[i];
        }
        float* mp = &mix2[nw * 65 + cq];
#pragma unroll
        for (int i = 0; i < 16; ++i) mp[i] = a[i];
    }
    for (int e = tid; e < 6 * 65; e += 256) mix2[34 * 65 + e] = 0.f;
    __syncthreads();

    // a2 = mix2 @ w2^T + b2 : per-thread 4 o (stride 32) x 5 nv
    int og = tid & 31, ng = tid >> 5;
    int nvbase = ng * 5;
    float accs[5][4];
#pragma unroll
    for (int i = 0; i < 5; ++i)
#pragma unroll
        for (int r = 0; r < 4; ++r) accs[i][r] = 0.f;
    for (int c4 = 0; c4 < 64; c4 += 4) {
        float wv[4][4];
#pragma unroll
        for (int r = 0; r < 4; ++r)
#pragma unroll
            for (int q = 0; q < 4; ++q) wv[r][q] = w2s[(c4 + q) * 129 + og + 32 * r];
#pragma unroll
        for (int i = 0; i < 5; ++i) {
            const float* mp = &mix2[(nvbase + i) * 65 + c4];
            float m0 = mp[0], m1 = mp[1], m2 = mp[2], m3 = mp[3];
#pragma unroll
            for (int r = 0; r < 4; ++r)
                accs[i][r] += m0 * wv[r][0] + m1 * wv[r][1] + m2 * wv[r][2] + m3 * wv[r][3];
        }
    }

    __hip_bfloat16* a2h = reinterpret_cast<__hip_bfloat16*>(h1);  // [34 nv][128 o] bf16 (8704 B)
    float b2r[4];
#pragma unroll
    for (int r = 0; r < 4; ++r) b2r[r] = b2[og + 32 * r];
    float s[4] = {0, 0, 0, 0}, q2[4] = {0, 0, 0, 0};
#pragma unroll
    for (int i = 0; i < 5; ++i) {
        int nv = nvbase + i;
        if (nv < 34) {
#pragma unroll
            for (int r = 0; r < 4; ++r) {
                float vv = accs[i][r] + b2r[r];
                s[r] += vv; q2[r] += vv * vv;
                a2h[nv * 128 + og + 32 * r] = __float2bfloat16(vv);
            }
        }
    }
#pragma unroll
    for (int r = 0; r < 4; ++r) {
        redS[ng * 128 + og + 32 * r] = s[r];
        redQ[ng * 128 + og + 32 * r] = q2[r];
    }
    __syncthreads();
    if (tid < 128) {
        float S = 0.f, Q = 0.f;
#pragma unroll
        for (int g = 0; g < 8; ++g) { S += redS[g * 128 + tid]; Q += redQ[g * 128 + tid]; }
        int slot = blockIdx.x & 15;
        atomicAdd(&st[2048 + slot * 128 + tid], S);
        atomicAdd(&st[4096 + slot * 128 + tid], Q);
    }

    // coalesced write: 34 rows x 256 B contiguous (16 threads x 16 B per row)
    __hip_bfloat16* zrb = zr + (size_t)b * (size_t)ZBv;
    int base_tv = t0 * 17;
    for (int e = tid; e < 544; e += 256) {
        int j = e >> 4, grp = e & 15;
        int tv = base_tv + j;
        int sf = tv & 511, q = tv >> 9;
        short8v val = *reinterpret_cast<const short8v*>(&a2h[j * 128 + grp * 8]);
        *reinterpret_cast<short8v*>(zrb + (size_t)sf * 2176 + q * 128 + grp * 8) = val;
    }
}

// in-place BN2 + ReLU on zr (bf16). With ci' = q*128+o, BN channel = ci' & 127.
// Each thread's channel set is loop-invariant (stride 2048 = 16*128) -> registers.
__global__ __launch_bounds__(256) void k_bn2(__hip_bfloat16* __restrict__ z,
                                             const float* __restrict__ sc2,
                                             const float* __restrict__ sh2) {
    int tid = threadIdx.x;
    int ch0 = (tid * 8) & 127;
    float sc[8], sh[8];
#pragma unroll
    for (int j = 0; j < 8; ++j) { sc[j] = sc2[ch0 + j]; sh[j] = sh2[ch0 + j]; }
    size_t base = (size_t)blockIdx.x * 2176;
    for (int g = tid; g < 272; g += 256) {
        int c = g * 8;
        short8v v = *reinterpret_cast<const short8v*>(z + base + c);
        short8v r;
#pragma unroll
        for (int j = 0; j < 8; ++j) {
            unsigned u = ((unsigned)(unsigned short)v[j]) << 16;
            float f = __uint_as_float(u);
            float t = fmaxf(f * sc[j] + sh[j], 0.f);
            __hip_bfloat16 h = __float2bfloat16(t);
            r[j] = *reinterpret_cast<short*>(&h);
        }
        *reinterpret_cast<short8v*>(z + base + c) = r;
    }
}

// MFMA temporal conv over folded axis: out[b][o][sf] = sum_k sum_ci' wkt[k][o][ci'] * zr[b][sf+k-1][ci']
__global__ __launch_bounds__(256, 3) void k_conv_mfma(const __hip_bfloat16* __restrict__ zr,
                                                      const __hip_bfloat16* __restrict__ wkt,
                                                      const float* __restrict__ bt,
                                                      float* __restrict__ cp,
                                                      float* __restrict__ s3,
                                                      float* __restrict__ ss3) {
    int tid = threadIdx.x;
    int b = blockIdx.x >> 3;
    int s0 = (blockIdx.x & 7) << 6;
    int wid = tid >> 6, lane = tid & 63;
    int l15 = lane & 15, l4 = lane >> 4;
    int m0 = (wid >> 1) * 64;
    int n0 = s0 + (wid & 1) * 32;

    f32x4 acc[4][2];
#pragma unroll
    for (int mi = 0; mi < 4; ++mi)
#pragma unroll
        for (int ni = 0; ni < 2; ++ni) acc[mi][ni] = (f32x4){0.f, 0.f, 0.f, 0.f};

    const __hip_bfloat16* aw = wkt + (size_t)l15 * 2176 + l4 * 8;
    const __hip_bfloat16* zb = zr + (size_t)b * 512 * 2176 + l4 * 8;
    size_t boff[3][2];
    int bok[3][2];
#pragma unroll
    for (int k = 0; k < 3; ++k)
#pragma unroll
        for (int ni = 0; ni < 2; ++ni) {
            int row = n0 + ni * 16 + l15 + k - 1;
            int ok = (unsigned)row < 512u;
            int rowc = ok ? row : 0;
            boff[k][ni] = (size_t)rowc * 2176;
            bok[k][ni] = ok;
        }

    for (int t = 0; t < 68; ++t) {
        int co = t * 32;
        short8v a_[3][4], b_[3][2];
#pragma unroll
        for (int k = 0; k < 3; ++k)
#pragma unroll
            for (int mi = 0; mi < 4; ++mi)
                a_[k][mi] = *reinterpret_cast<const short8v*>(
                    aw + (size_t)(k * 128 + m0 + mi * 16) * 2176 + co);
#pragma unroll
        for (int k = 0; k < 3; ++k)
#pragma unroll
            for (int ni = 0; ni < 2; ++ni) {
                short8v bv = *reinterpret_cast<const short8v*>(zb + boff[k][ni] + co);
                if (!bok[k][ni]) bv = (short8v)0;
                b_[k][ni] = bv;
            }
#pragma unroll
        for (int k = 0; k < 3; ++k)
#pragma unroll
            for (int mi = 0; mi < 4; ++mi)
#pragma unroll
                for (int ni = 0; ni < 2; ++ni)
                    acc[mi][ni] = __builtin_amdgcn_mfma_f32_16x16x32_bf16(
                        a_[k][mi], b_[k][ni], acc[mi][ni], 0, 0, 0);
    }

    int slot = blockIdx.x & 15;
#pragma unroll
    for (int mi = 0; mi < 4; ++mi)
#pragma unroll
        for (int r = 0; r < 4; ++r) {
            int o = m0 + mi * 16 + l4 * 4 + r;
            float btv = bt[o];
            float v0 = acc[mi][0][r] + btv;
            float v1 = acc[mi][1][r] + btv;
            size_t cb = ((size_t)(b * 128 + o)) * 512 + n0 + l15;
            cp[cb] = v0;
            cp[cb + 16] = v1;
            float sv = v0 + v1;
            float sq = v0 * v0 + v1 * v1;
#pragma unroll
            for (int off = 1; off < 16; off <<= 1) {
                sv += __shfl_xor(sv, off, 64);
                sq += __shfl_xor(sq, off, 64);
            }
            if (l15 == 0) {
                atomicAdd(&s3[slot * 128 + o], sv);
                atomicAdd(&ss3[slot * 128 + o], sq);
            }
        }
}

__global__ __launch_bounds__(256) void k_out(const float* __restrict__ cp,
                                             const float* __restrict__ sc3,
                                             const float* __restrict__ sh3,
                                             float* __restrict__ out) {
    __shared__ float tile[128 * 33];
    int tid = threadIdx.x;
    int b = blockIdx.x >> 4;
    int t0 = (blockIdx.x & 15) * 32;
    for (int e = tid; e < 128 * 32; e += 256) {
        int o = e >> 5, tj = e & 31;
        tile[o * 33 + tj] = cp[((size_t)b * 128 + o) * 512 + t0 + tj];
    }
    __syncthreads();
    for (int e = tid; e < 128 * 32; e += 256) {
        int o = e & 127, th = e >> 7;
        float v = tile[o * 33 + th] * sc3[o] + sh3[o];
        out[((size_t)b * 512 + t0 + th) * 128 + o] = fmaxf(v, 0.f);
    }
}

extern "C" void kernel_launch(void* const* d_in, const int* in_sizes, int n_in,
                              void* d_out, int out_size, void* d_ws, size_t ws_size,
                              hipStream_t stream) {
    const float* x   = (const float*)d_in[0];
    const float* adj = (const float*)d_in[1];
    const float* w1  = (const float*)d_in[2];
    const float* b1  = (const float*)d_in[3];
    const float* g1  = (const float*)d_in[4];
    const float* be1 = (const float*)d_in[5];
    const float* w2  = (const float*)d_in[6];
    const float* b2  = (const float*)d_in[7];
    const float* g2  = (const float*)d_in[8];
    const float* be2 = (const float*)d_in[9];
    const float* wt  = (const float*)d_in[10];
    const float* bt  = (const float*)d_in[11];
    const float* gt  = (const float*)d_in[12];
    const float* bet = (const float*)d_in[13];
    float* out = (float*)d_out;

    char* ws = (char*)d_ws;
    __hip_bfloat16* zr  = (__hip_bfloat16*)(ws + OFF_ZR);
    __hip_bfloat16* wkt = (__hip_bfloat16*)(ws + OFF_WKT);
    float* cp = (float*)(ws + OFF_CP);
    float* st = (float*)(ws + OFF_ST);

    hipMemsetAsync(st, 0, 10240 * sizeof(float), stream);

    k_wt_bf16<<<dim3(3264), dim3(256), 0, stream>>>(wt, wkt);
    k_stats1<<<dim3(1024), dim3(256), 0, stream>>>(x, adj, w1, b1, st);
    k_finalize<<<dim3(1), dim3(128), 0, stream>>>(st, st + 1024, g1, be1,
                                                  st + 10240, st + 10304, 64, 1.f / 557056.f);
    k_gcn<<<dim3(16384), dim3(256), 0, stream>>>(x, adj, w1, b1,
                                                 st + 10240, st + 10304,
                                                 w2, b2, st, zr);
    k_finalize<<<dim3(1), dim3(128), 0, stream>>>(st + 2048, st + 4096, g2, be2,
                                                  st + 10368, st + 10496, 128, 1.f / 557056.f);
    k_bn2<<<dim3(32768), dim3(256), 0, stream>>>(zr, st + 10368, st + 10496);
    k_conv_mfma<<<dim3(512), dim3(256), 0, stream>>>(zr, wkt, bt,
                                                     cp, st + 6144, st + 8192);
    k_finalize<<<dim3(1), dim3(128), 0, stream>>>(st + 6144, st + 8192, gt, bet,
                                                  st + 10624, st + 10752, 128, 1.f / 32768.f);
    k_out<<<dim3(1024), dim3(256), 0, stream>>>(cp, st + 10624, st + 10752, out);
}

// Round 6
// 606.594 us; speedup vs baseline: 2.9168x; 1.1470x over previous
//
#include <hip/hip_runtime.h>
#include <hip/hip_bf16.h>

#define EPS 1e-5f

static constexpr int Bv = 64, Tv = 512, Vv = 17, Hv = 128;
static constexpr int CHv = Hv * Vv;                // 2176
static constexpr long ZBv = (long)CHv * Tv;        // 1114112 elems per batch

typedef __attribute__((ext_vector_type(8))) short short8v;
typedef __attribute__((ext_vector_type(4))) float f32x4;

// ---- workspace layout (~161 MB) ----
// Channel axis PERMUTED: ci' = q*128 + o  (orig ci = o*17 + q).
static constexpr size_t SZ_Z    = (size_t)Bv * (size_t)ZBv * 2;      // 142,606,336
static constexpr size_t OFF_ZR  = 0;                                  // zr [b][sf][ci'] bf16
static constexpr size_t OFF_WKT = OFF_ZR + SZ_Z;                      // bf16 [k][o_out][ci']
static constexpr size_t SZ_WKT  = (size_t)3 * 128 * 2176 * 2;        // 1,671,168
static constexpr size_t OFF_W2B = OFF_WKT + SZ_WKT;                   // bf16 w2 [128][64]
static constexpr size_t SZ_W2B  = (size_t)128 * 64 * 2;              // 16,384
static constexpr size_t OFF_CP  = OFF_W2B + SZ_W2B;                   // f32 conv out [b][o][sf]
static constexpr size_t SZ_CP   = (size_t)Bv * Hv * Tv * 4;          // 16,777,216
static constexpr size_t OFF_ST  = OFF_CP + SZ_CP;
// stats floats:
//  0:s1sp[1024] 1024:ss1sp 2048:s2sp[2048] 4096:ss2sp 6144:s3sp[2048] 8192:ss3sp
//  10240:sc1[64] 10304:sh1[64] 10368:sc2[128] 10496:sh2[128] 10624:sc3[128] 10752:sh3[128]

__global__ __launch_bounds__(256) void k_wt_bf16(const float* __restrict__ wt,
                                                 __hip_bfloat16* __restrict__ wkt) {
    int e = blockIdx.x * 256 + threadIdx.x;   // e = (k*128+o_out)*2176 + ci'
    if (e >= 3 * 128 * 2176) return;
    int cip = e % 2176;
    int ko = e / 2176;
    int o_out = ko % 128, k = ko / 128;
    int q = cip >> 7, o_in = cip & 127;        // ci' = q*128 + o_in
    int orig_ck = (o_in * 17 + q) * 3 + k;
    wkt[e] = __float2bfloat16(wt[(size_t)o_out * 6528 + orig_ck]);
}

__global__ __launch_bounds__(256) void k_w2b(const float* __restrict__ w2,
                                             __hip_bfloat16* __restrict__ w2b) {
    int e = blockIdx.x * 256 + threadIdx.x;
    if (e >= 8192) return;
    w2b[e] = __float2bfloat16(w2[e]);
}

__global__ __launch_bounds__(256) void k_stats1(const float* __restrict__ x,
                                                const float* __restrict__ adj,
                                                const float* __restrict__ w1,
                                                const float* __restrict__ b1,
                                                float* __restrict__ st) {
    __shared__ float adj_s[289];
    __shared__ float xs[32 * 34];
    __shared__ float mix[32 * 34];
    __shared__ float red[256], red2[256];
    int tid = threadIdx.x;
    int n0 = blockIdx.x * 32;
    for (int i = tid; i < 289; i += 256) adj_s[i] = adj[i];
    for (int i = tid; i < 1088; i += 256) xs[i] = x[(size_t)n0 * 34 + i];
    __syncthreads();
    for (int e = tid; e < 1088; e += 256) {
        int n = e / 34, r = e % 34;
        int w = r >> 1, c = r & 1;
        float acc = 0.f;
        for (int v = 0; v < 17; ++v) acc += xs[n * 34 + v * 2 + c] * adj_s[v * 17 + w];
        mix[n * 34 + w * 2 + c] = acc;
    }
    __syncthreads();
    int o = tid & 63, g = tid >> 6;
    float w0 = w1[o * 2], w1v = w1[o * 2 + 1], bb = b1[o];
    float s = 0.f, s2 = 0.f;
    for (int n = g; n < 32; n += 4)
        for (int v = 0; v < 17; ++v) {
            float a = mix[n * 34 + v * 2] * w0 + mix[n * 34 + v * 2 + 1] * w1v + bb;
            s += a; s2 += a * a;
        }
    red[tid] = s; red2[tid] = s2;
    __syncthreads();
    if (tid < 64) {
        float S  = red[tid] + red[tid + 64] + red[tid + 128] + red[tid + 192];
        float S2 = red2[tid] + red2[tid + 64] + red2[tid + 128] + red2[tid + 192];
        int slot = blockIdx.x & 15;
        atomicAdd(&st[slot * 64 + o], S);
        atomicAdd(&st[1024 + slot * 64 + o], S2);
    }
}

__global__ void k_finalize(const float* __restrict__ sums, const float* __restrict__ sumsq,
                           const float* __restrict__ gamma, const float* __restrict__ beta,
                           float* __restrict__ scale, float* __restrict__ shift,
                           int count, float inv_denom) {
    int o = threadIdx.x;
    if (o >= count) return;
    float S = 0.f, Q = 0.f;
    for (int j = 0; j < 16; ++j) { S += sums[j * count + o]; Q += sumsq[j * count + o]; }
    float m = S * inv_denom;
    float var = Q * inv_denom - m * m;
    float rstd = rsqrtf(var + EPS);
    float sc = rstd * gamma[o];
    scale[o] = sc;
    shift[o] = beta[o] - m * sc;
}

// MFMA GCN: block = (b, 64 folded rows tv=r0..r0+63). 4 waves.
// Pipeline: x -> mix1 -> h1(BN1,relu) -> mix2 -> bf16 -> MFMA vs w2 -> stats -> zr.
__global__ __launch_bounds__(256) void k_gcn(const float* __restrict__ x,
                                             const float* __restrict__ adj,
                                             const float* __restrict__ w1,
                                             const float* __restrict__ b1,
                                             const float* __restrict__ sc1,
                                             const float* __restrict__ sh1,
                                             const __hip_bfloat16* __restrict__ w2b,
                                             const float* __restrict__ b2,
                                             float* __restrict__ st,
                                             __hip_bfloat16* __restrict__ zr) {
    __shared__ float adj_s[289];
    __shared__ float xs[170];
    __shared__ float mix1[170];
    __shared__ __align__(16) float h1[85 * 68];           // 23.1KB; later aliased bf16 a2st[64][136]
    __shared__ __align__(16) __hip_bfloat16 m2b[64 * 80]; // 10.2KB

    int tid = threadIdx.x;
    int bi = blockIdx.x;
    int b = bi / 136, rb = bi - b * 136;
    int r0 = rb * 64;
    int t_lo = r0 / 17;

    for (int i = tid; i < 289; i += 256) adj_s[i] = adj[i];
    for (int i = tid; i < 170; i += 256) {
        int tt = i / 34, r = i - tt * 34;
        int t = min(t_lo + tt, 511);
        xs[i] = x[(size_t)(b * 512 + t) * 34 + r];
    }
    __syncthreads();

    // mix1 [5][34]
    for (int e = tid; e < 170; e += 256) {
        int n = e / 34, r = e % 34, w = r >> 1, c = r & 1;
        float acc = 0.f;
        for (int v = 0; v < 17; ++v) acc += xs[n * 34 + v * 2 + c] * adj_s[v * 17 + w];
        mix1[n * 34 + w * 2 + c] = acc;
    }
    __syncthreads();

    // h1 [85][64]: relu(BN1(mix1 @ w1^T + b1))
    for (int e = tid; e < 85 * 64; e += 256) {
        int row = e >> 6, o = e & 63;
        int n = row / 17, v = row - n * 17;
        float a = mix1[n * 34 + v * 2] * w1[o * 2] + mix1[n * 34 + v * 2 + 1] * w1[o * 2 + 1] + b1[o];
        a = a * sc1[o] + sh1[o];
        h1[row * 68 + o] = fmaxf(a, 0.f);
    }
    __syncthreads();

    // mix2 rows r0..r0+63 -> m2b bf16 [64][80]; thread = (row j, 16-ch chunk)
    {
        int j = tid >> 2, cq = (tid & 3) << 4;
        int tv = r0 + j;
        int t = tv / 17, w = tv - t * 17;
        int base = (t - t_lo) * 17;
        float a[16];
#pragma unroll
        for (int i = 0; i < 16; ++i) a[i] = 0.f;
        for (int v = 0; v < 17; ++v) {
            float ad = adj_s[v * 17 + w];
            const float* hp = &h1[(base + v) * 68 + cq];
#pragma unroll
            for (int i = 0; i < 16; ++i) a[i] += ad * hp[i];
        }
        __hip_bfloat16* mp = &m2b[j * 80 + cq];
#pragma unroll
        for (int i = 0; i < 16; ++i) mp[i] = __float2bfloat16(a[i]);
    }
    __syncthreads();

    // MFMA: a2[128 o][64 rows] = w2 @ mix2^T. Wave: 64 o x 32 rows.
    int wid = tid >> 6, lane = tid & 63;
    int l15 = lane & 15, l4 = lane >> 4;
    int m0 = (wid >> 1) * 64, nh = (wid & 1) * 32;

    short8v afr[4][2];
#pragma unroll
    for (int mi = 0; mi < 4; ++mi)
#pragma unroll
        for (int kk = 0; kk < 2; ++kk)
            afr[mi][kk] = *reinterpret_cast<const short8v*>(
                w2b + (size_t)(m0 + mi * 16 + l15) * 64 + kk * 32 + l4 * 8);

    f32x4 acc[4][2];
#pragma unroll
    for (int mi = 0; mi < 4; ++mi)
#pragma unroll
        for (int ni = 0; ni < 2; ++ni) acc[mi][ni] = (f32x4){0.f, 0.f, 0.f, 0.f};

#pragma unroll
    for (int kk = 0; kk < 2; ++kk)
#pragma unroll
        for (int ni = 0; ni < 2; ++ni) {
            short8v bfr = *reinterpret_cast<const short8v*>(
                &m2b[(nh + ni * 16 + l15) * 80 + kk * 32 + l4 * 8]);
#pragma unroll
            for (int mi = 0; mi < 4; ++mi)
                acc[mi][ni] = __builtin_amdgcn_mfma_f32_16x16x32_bf16(
                    afr[mi][kk], bfr, acc[mi][ni], 0, 0, 0);
        }

    // epilogue: bias, stats, stage a2 (aliased over h1)
    __hip_bfloat16* a2st = reinterpret_cast<__hip_bfloat16*>(h1);  // [64][136]
    int slot = bi & 15;
#pragma unroll
    for (int mi = 0; mi < 4; ++mi)
#pragma unroll
        for (int r = 0; r < 4; ++r) {
            int o = m0 + mi * 16 + l4 * 4 + r;
            float bb = b2[o];
            float v0 = acc[mi][0][r] + bb;
            float v1 = acc[mi][1][r] + bb;
            a2st[(nh + l15) * 136 + o]      = __float2bfloat16(v0);
            a2st[(nh + 16 + l15) * 136 + o] = __float2bfloat16(v1);
            float sv = v0 + v1;
            float sq = v0 * v0 + v1 * v1;
#pragma unroll
            for (int off = 1; off < 16; off <<= 1) {
                sv += __shfl_xor(sv, off, 64);
                sq += __shfl_xor(sq, off, 64);
            }
            if (l15 == 0) {
                atomicAdd(&st[2048 + slot * 128 + o], sv);
                atomicAdd(&st[4096 + slot * 128 + o], sq);
            }
        }
    __syncthreads();

    // coalesced zr write: 64 rows x 256B
    __hip_bfloat16* zrb = zr + (size_t)b * (size_t)ZBv;
    for (int e = tid; e < 1024; e += 256) {
        int j = e >> 4, grp = e & 15;
        int tv = r0 + j;
        int sf = tv & 511, q = tv >> 9;
        short8v val = *reinterpret_cast<const short8v*>(&a2st[j * 136 + grp * 8]);
        *reinterpret_cast<short8v*>(zrb + (size_t)sf * 2176 + q * 128 + grp * 8) = val;
    }
}

// in-place BN2 + ReLU on zr (bf16). BN channel = ci' & 127.
__global__ __launch_bounds__(256) void k_bn2(__hip_bfloat16* __restrict__ z,
                                             const float* __restrict__ sc2,
                                             const float* __restrict__ sh2) {
    int tid = threadIdx.x;
    int ch0 = (tid * 8) & 127;
    float sc[8], sh[8];
#pragma unroll
    for (int j = 0; j < 8; ++j) { sc[j] = sc2[ch0 + j]; sh[j] = sh2[ch0 + j]; }
    size_t base = (size_t)blockIdx.x * 2176;
    for (int g = tid; g < 272; g += 256) {
        int c = g * 8;
        short8v v = *reinterpret_cast<const short8v*>(z + base + c);
        short8v r;
#pragma unroll
        for (int j = 0; j < 8; ++j) {
            unsigned u = ((unsigned)(unsigned short)v[j]) << 16;
            float f = __uint_as_float(u);
            float t = fmaxf(f * sc[j] + sh[j], 0.f);
            __hip_bfloat16 h = __float2bfloat16(t);
            r[j] = *reinterpret_cast<short*>(&h);
        }
        *reinterpret_cast<short8v*>(z + base + c) = r;
    }
}

// MFMA temporal conv: out[b][o][sf] = sum_k sum_ci' wkt[k][o][ci'] * zr[b][sf+k-1][ci']
__global__ __launch_bounds__(256, 3) void k_conv_mfma(const __hip_bfloat16* __restrict__ zr,
                                                      const __hip_bfloat16* __restrict__ wkt,
                                                      const float* __restrict__ bt,
                                                      float* __restrict__ cp,
                                                      float* __restrict__ s3,
                                                      float* __restrict__ ss3) {
    int tid = threadIdx.x;
    int b = blockIdx.x >> 3;
    int s0 = (blockIdx.x & 7) << 6;
    int wid = tid >> 6, lane = tid & 63;
    int l15 = lane & 15, l4 = lane >> 4;
    int m0 = (wid >> 1) * 64;
    int n0 = s0 + (wid & 1) * 32;

    f32x4 acc[4][2];
#pragma unroll
    for (int mi = 0; mi < 4; ++mi)
#pragma unroll
        for (int ni = 0; ni < 2; ++ni) acc[mi][ni] = (f32x4){0.f, 0.f, 0.f, 0.f};

    const __hip_bfloat16* aw = wkt + (size_t)l15 * 2176 + l4 * 8;
    const __hip_bfloat16* zb = zr + (size_t)b * 512 * 2176 + l4 * 8;
    size_t boff[3][2];
    int bok[3][2];
#pragma unroll
    for (int k = 0; k < 3; ++k)
#pragma unroll
        for (int ni = 0; ni < 2; ++ni) {
            int row = n0 + ni * 16 + l15 + k - 1;
            int ok = (unsigned)row < 512u;
            int rowc = ok ? row : 0;
            boff[k][ni] = (size_t)rowc * 2176;
            bok[k][ni] = ok;
        }

    for (int t = 0; t < 68; ++t) {
        int co = t * 32;
        short8v a_[3][4], b_[3][2];
#pragma unroll
        for (int k = 0; k < 3; ++k)
#pragma unroll
            for (int mi = 0; mi < 4; ++mi)
                a_[k][mi] = *reinterpret_cast<const short8v*>(
                    aw + (size_t)(k * 128 + m0 + mi * 16) * 2176 + co);
#pragma unroll
        for (int k = 0; k < 3; ++k)
#pragma unroll
            for (int ni = 0; ni < 2; ++ni) {
                short8v bv = *reinterpret_cast<const short8v*>(zb + boff[k][ni] + co);
                if (!bok[k][ni]) bv = (short8v)0;
                b_[k][ni] = bv;
            }
#pragma unroll
        for (int k = 0; k < 3; ++k)
#pragma unroll
            for (int mi = 0; mi < 4; ++mi)
#pragma unroll
                for (int ni = 0; ni < 2; ++ni)
                    acc[mi][ni] = __builtin_amdgcn_mfma_f32_16x16x32_bf16(
                        a_[k][mi], b_[k][ni], acc[mi][ni], 0, 0, 0);
    }

    int slot = blockIdx.x & 15;
#pragma unroll
    for (int mi = 0; mi < 4; ++mi)
#pragma unroll
        for (int r = 0; r < 4; ++r) {
            int o = m0 + mi * 16 + l4 * 4 + r;
            float btv = bt[o];
            float v0 = acc[mi][0][r] + btv;
            float v1 = acc[mi][1][r] + btv;
            size_t cb = ((size_t)(b * 128 + o)) * 512 + n0 + l15;
            cp[cb] = v0;
            cp[cb + 16] = v1;
            float sv = v0 + v1;
            float sq = v0 * v0 + v1 * v1;
#pragma unroll
            for (int off = 1; off < 16; off <<= 1) {
                sv += __shfl_xor(sv, off, 64);
                sq += __shfl_xor(sq, off, 64);
            }
            if (l15 == 0) {
                atomicAdd(&s3[slot * 128 + o], sv);
                atomicAdd(&ss3[slot * 128 + o], sq);
            }
        }
}

__global__ __launch_bounds__(256) void k_out(const float* __restrict__ cp,
                                             const float* __restrict__ sc3,
                                             const float* __restrict__ sh3,
                                             float* __restrict__ out) {
    __shared__ float tile[128 * 33];
    int tid = threadIdx.x;
    int b = blockIdx.x >> 4;
    int t0 = (blockIdx.x & 15) * 32;
    for (int e = tid; e < 128 * 32; e += 256) {
        int o = e >> 5, tj = e & 31;
        tile[o * 33 + tj] = cp[((size_t)b * 128 + o) * 512 + t0 + tj];
    }
    __syncthreads();
    for (int e = tid; e < 128 * 32; e += 256) {
        int o = e & 127, th = e >> 7;
        float v = tile[o * 33 + th] * sc3[o] + sh3[o];
        out[((size_t)b * 512 + t0 + th) * 128 + o] = fmaxf(v, 0.f);
    }
}

extern "C" void kernel_launch(void* const* d_in, const int* in_sizes, int n_in,
                              void* d_out, int out_size, void* d_ws, size_t ws_size,
                              hipStream_t stream) {
    const float* x   = (const float*)d_in[0];
    const float* adj = (const float*)d_in[1];
    const float* w1  = (const float*)d_in[2];
    const float* b1  = (const float*)d_in[3];
    const float* g1  = (const float*)d_in[4];
    const float* be1 = (const float*)d_in[5];
    const float* w2  = (const float*)d_in[6];
    const float* b2  = (const float*)d_in[7];
    const float* g2  = (const float*)d_in[8];
    const float* be2 = (const float*)d_in[9];
    const float* wt  = (const float*)d_in[10];
    const float* bt  = (const float*)d_in[11];
    const float* gt  = (const float*)d_in[12];
    const float* bet = (const float*)d_in[13];
    float* out = (float*)d_out;

    char* ws = (char*)d_ws;
    __hip_bfloat16* zr  = (__hip_bfloat16*)(ws + OFF_ZR);
    __hip_bfloat16* wkt = (__hip_bfloat16*)(ws + OFF_WKT);
    __hip_bfloat16* w2b = (__hip_bfloat16*)(ws + OFF_W2B);
    float* cp = (float*)(ws + OFF_CP);
    float* st = (float*)(ws + OFF_ST);

    hipMemsetAsync(st, 0, 10240 * sizeof(float), stream);

    k_wt_bf16<<<dim3(3264), dim3(256), 0, stream>>>(wt, wkt);
    k_w2b<<<dim3(32), dim3(256), 0, stream>>>(w2, w2b);
    k_stats1<<<dim3(1024), dim3(256), 0, stream>>>(x, adj, w1, b1, st);
    k_finalize<<<dim3(1), dim3(128), 0, stream>>>(st, st + 1024, g1, be1,
                                                  st + 10240, st + 10304, 64, 1.f / 557056.f);
    k_gcn<<<dim3(8704), dim3(256), 0, stream>>>(x, adj, w1, b1,
                                                st + 10240, st + 10304,
                                                w2b, b2, st, zr);
    k_finalize<<<dim3(1), dim3(128), 0, stream>>>(st + 2048, st + 4096, g2, be2,
                                                  st + 10368, st + 10496, 128, 1.f / 557056.f);
    k_bn2<<<dim3(32768), dim3(256), 0, stream>>>(zr, st + 10368, st + 10496);
    k_conv_mfma<<<dim3(512), dim3(256), 0, stream>>>(zr, wkt, bt,
                                                     cp, st + 6144, st + 8192);
    k_finalize<<<dim3(1), dim3(128), 0, stream>>>(st + 6144, st + 8192, gt, bet,
                                                  st + 10624, st + 10752, 128, 1.f / 32768.f);
    k_out<<<dim3(1024), dim3(256), 0, stream>>>(cp, st + 10624, st + 10752, out);
}

// Round 7
// 415.180 us; speedup vs baseline: 4.2616x; 1.4610x over previous
//
#include <hip/hip_runtime.h>
#include <hip/hip_bf16.h>

#define EPS 1e-5f

static constexpr int Bv = 64, Tv = 512, Vv = 17, Hv = 128;
static constexpr int CHv = Hv * Vv;                // 2176
static constexpr long ZBv = (long)CHv * Tv;        // 1114112 elems per batch

typedef __attribute__((ext_vector_type(8))) short short8v;
typedef __attribute__((ext_vector_type(4))) float f32x4;
typedef __attribute__((ext_vector_type(4))) int   int4v;

// ---- workspace layout (~161 MB) ----
// zr2: fragment-tiled bf16 [b][sfT(32)][ciC(68)][lane(64)][e(8)]
//      holds z[b][sf = sfT*16 + (lane&15)][ci' = ciC*32 + (lane>>4)*8 + e]
//      (ci' = q*128 + o permuted channel, q = tv>>9)
// wkt2: fragment-tiled bf16 [k(3)][oT(8)][ciC(68)][lane(64)][e(8)]
static constexpr size_t SZ_Z    = (size_t)Bv * (size_t)ZBv * 2;      // 142,606,336
static constexpr size_t OFF_ZR  = 0;
static constexpr size_t OFF_WKT = OFF_ZR + SZ_Z;
static constexpr size_t SZ_WKT  = (size_t)3 * 128 * 2176 * 2;        // 1,671,168
static constexpr size_t OFF_W2B = OFF_WKT + SZ_WKT;                   // bf16 w2 [128][64]
static constexpr size_t SZ_W2B  = (size_t)128 * 64 * 2;
static constexpr size_t OFF_CP  = OFF_W2B + SZ_W2B;                   // f32 conv out [b][o][sf]
static constexpr size_t SZ_CP   = (size_t)Bv * Hv * Tv * 4;          // 16,777,216
static constexpr size_t OFF_ST  = OFF_CP + SZ_CP;
// stats floats:
//  0:s1sp[1024] 1024:ss1sp 2048:s2sp[2048] 4096:ss2sp 6144:s3sp[2048] 8192:ss3sp
//  10240:sc1[64] 10304:sh1[64] 10368:sc2[128] 10496:sh2[128] 10624:sc3[128] 10752:sh3[128]

__device__ __forceinline__ int4v ld16(const __hip_bfloat16* p) {
    return *reinterpret_cast<const int4v*>(p);
}
__device__ __forceinline__ f32x4 mfma16(int4v a, int4v b, f32x4 c) {
    return __builtin_amdgcn_mfma_f32_16x16x32_bf16(
        *reinterpret_cast<short8v*>(&a), *reinterpret_cast<short8v*>(&b), c, 0, 0, 0);
}

// build wkt2 in fragment-tiled order
__global__ __launch_bounds__(256) void k_wt_bf16(const float* __restrict__ wt,
                                                 __hip_bfloat16* __restrict__ wkt2) {
    int i = blockIdx.x * 256 + threadIdx.x;
    if (i >= 3 * 128 * 2176) return;
    int el = i & 7;
    int ln = (i >> 3) & 63;
    int r  = i >> 9;            // ((k*8 + oT)*68 + c)
    int c  = r % 68; r /= 68;
    int oT = r & 7;  int k = r >> 3;
    int o   = oT * 16 + (ln & 15);
    int cip = c * 32 + ((ln >> 4) << 3) + el;
    int q = cip >> 7, o_in = cip & 127;
    wkt2[i] = __float2bfloat16(wt[(size_t)o * 6528 + (o_in * 17 + q) * 3 + k]);
}

__global__ __launch_bounds__(256) void k_w2b(const float* __restrict__ w2,
                                             __hip_bfloat16* __restrict__ w2b) {
    int e = blockIdx.x * 256 + threadIdx.x;
    if (e >= 8192) return;
    w2b[e] = __float2bfloat16(w2[e]);
}

__global__ __launch_bounds__(256) void k_stats1(const float* __restrict__ x,
                                                const float* __restrict__ adj,
                                                const float* __restrict__ w1,
                                                const float* __restrict__ b1,
                                                float* __restrict__ st) {
    __shared__ float adj_s[289];
    __shared__ float xs[32 * 34];
    __shared__ float mix[32 * 34];
    __shared__ float red[256], red2[256];
    int tid = threadIdx.x;
    int n0 = blockIdx.x * 32;
    for (int i = tid; i < 289; i += 256) adj_s[i] = adj[i];
    for (int i = tid; i < 1088; i += 256) xs[i] = x[(size_t)n0 * 34 + i];
    __syncthreads();
    for (int e = tid; e < 1088; e += 256) {
        int n = e / 34, r = e % 34;
        int w = r >> 1, c = r & 1;
        float acc = 0.f;
        for (int v = 0; v < 17; ++v) acc += xs[n * 34 + v * 2 + c] * adj_s[v * 17 + w];
        mix[n * 34 + w * 2 + c] = acc;
    }
    __syncthreads();
    int o = tid & 63, g = tid >> 6;
    float w0 = w1[o * 2], w1v = w1[o * 2 + 1], bb = b1[o];
    float s = 0.f, s2 = 0.f;
    for (int n = g; n < 32; n += 4)
        for (int v = 0; v < 17; ++v) {
            float a = mix[n * 34 + v * 2] * w0 + mix[n * 34 + v * 2 + 1] * w1v + bb;
            s += a; s2 += a * a;
        }
    red[tid] = s; red2[tid] = s2;
    __syncthreads();
    if (tid < 64) {
        float S  = red[tid] + red[tid + 64] + red[tid + 128] + red[tid + 192];
        float S2 = red2[tid] + red2[tid + 64] + red2[tid + 128] + red2[tid + 192];
        int slot = blockIdx.x & 15;
        atomicAdd(&st[slot * 64 + o], S);
        atomicAdd(&st[1024 + slot * 64 + o], S2);
    }
}

__global__ void k_finalize(const float* __restrict__ sums, const float* __restrict__ sumsq,
                           const float* __restrict__ gamma, const float* __restrict__ beta,
                           float* __restrict__ scale, float* __restrict__ shift,
                           int count, float inv_denom) {
    int o = threadIdx.x;
    if (o >= count) return;
    float S = 0.f, Q = 0.f;
    for (int j = 0; j < 16; ++j) { S += sums[j * count + o]; Q += sumsq[j * count + o]; }
    float m = S * inv_denom;
    float var = Q * inv_denom - m * m;
    float rstd = rsqrtf(var + EPS);
    float sc = rstd * gamma[o];
    scale[o] = sc;
    shift[o] = beta[o] - m * sc;
}

// MFMA GCN: block = (b, 64 folded rows tv=r0..r0+63). 4 waves.
__global__ __launch_bounds__(256) void k_gcn(const float* __restrict__ x,
                                             const float* __restrict__ adj,
                                             const float* __restrict__ w1,
                                             const float* __restrict__ b1,
                                             const float* __restrict__ sc1,
                                             const float* __restrict__ sh1,
                                             const __hip_bfloat16* __restrict__ w2b,
                                             const float* __restrict__ b2,
                                             float* __restrict__ st,
                                             __hip_bfloat16* __restrict__ zr2) {
    __shared__ float adj_s[289];
    __shared__ float xs[170];
    __shared__ float mix1[170];
    __shared__ __align__(16) float h1[85 * 68];           // later aliased bf16 a2st[64][136]
    __shared__ __align__(16) __hip_bfloat16 m2b[64 * 80];

    int tid = threadIdx.x;
    int bi = blockIdx.x;
    int b = bi / 136, rb = bi - b * 136;
    int r0 = rb * 64;
    int t_lo = r0 / 17;

    for (int i = tid; i < 289; i += 256) adj_s[i] = adj[i];
    for (int i = tid; i < 170; i += 256) {
        int tt = i / 34, r = i - tt * 34;
        int t = min(t_lo + tt, 511);
        xs[i] = x[(size_t)(b * 512 + t) * 34 + r];
    }
    __syncthreads();

    for (int e = tid; e < 170; e += 256) {
        int n = e / 34, r = e % 34, w = r >> 1, c = r & 1;
        float acc = 0.f;
        for (int v = 0; v < 17; ++v) acc += xs[n * 34 + v * 2 + c] * adj_s[v * 17 + w];
        mix1[n * 34 + w * 2 + c] = acc;
    }
    __syncthreads();

    for (int e = tid; e < 85 * 64; e += 256) {
        int row = e >> 6, o = e & 63;
        int n = row / 17, v = row - n * 17;
        float a = mix1[n * 34 + v * 2] * w1[o * 2] + mix1[n * 34 + v * 2 + 1] * w1[o * 2 + 1] + b1[o];
        a = a * sc1[o] + sh1[o];
        h1[row * 68 + o] = fmaxf(a, 0.f);
    }
    __syncthreads();

    {
        int j = tid >> 2, cq = (tid & 3) << 4;
        int tv = r0 + j;
        int t = tv / 17, w = tv - t * 17;
        int base = (t - t_lo) * 17;
        float a[16];
#pragma unroll
        for (int i = 0; i < 16; ++i) a[i] = 0.f;
        for (int v = 0; v < 17; ++v) {
            float ad = adj_s[v * 17 + w];
            const float* hp = &h1[(base + v) * 68 + cq];
#pragma unroll
            for (int i = 0; i < 16; ++i) a[i] += ad * hp[i];
        }
        __hip_bfloat16* mp = &m2b[j * 80 + cq];
#pragma unroll
        for (int i = 0; i < 16; ++i) mp[i] = __float2bfloat16(a[i]);
    }
    __syncthreads();

    int wid = tid >> 6, lane = tid & 63;
    int l15 = lane & 15, l4 = lane >> 4;
    int m0 = (wid >> 1) * 64, nh = (wid & 1) * 32;

    short8v afr[4][2];
#pragma unroll
    for (int mi = 0; mi < 4; ++mi)
#pragma unroll
        for (int kk = 0; kk < 2; ++kk)
            afr[mi][kk] = *reinterpret_cast<const short8v*>(
                w2b + (size_t)(m0 + mi * 16 + l15) * 64 + kk * 32 + l4 * 8);

    f32x4 acc[4][2];
#pragma unroll
    for (int mi = 0; mi < 4; ++mi)
#pragma unroll
        for (int ni = 0; ni < 2; ++ni) acc[mi][ni] = (f32x4){0.f, 0.f, 0.f, 0.f};

#pragma unroll
    for (int kk = 0; kk < 2; ++kk)
#pragma unroll
        for (int ni = 0; ni < 2; ++ni) {
            short8v bfr = *reinterpret_cast<const short8v*>(
                &m2b[(nh + ni * 16 + l15) * 80 + kk * 32 + l4 * 8]);
#pragma unroll
            for (int mi = 0; mi < 4; ++mi)
                acc[mi][ni] = __builtin_amdgcn_mfma_f32_16x16x32_bf16(
                    afr[mi][kk], bfr, acc[mi][ni], 0, 0, 0);
        }

    __hip_bfloat16* a2st = reinterpret_cast<__hip_bfloat16*>(h1);  // [64][136]
    int slot = bi & 15;
#pragma unroll
    for (int mi = 0; mi < 4; ++mi)
#pragma unroll
        for (int r = 0; r < 4; ++r) {
            int o = m0 + mi * 16 + l4 * 4 + r;
            float bb = b2[o];
            float v0 = acc[mi][0][r] + bb;
            float v1 = acc[mi][1][r] + bb;
            a2st[(nh + l15) * 136 + o]      = __float2bfloat16(v0);
            a2st[(nh + 16 + l15) * 136 + o] = __float2bfloat16(v1);
            float sv = v0 + v1;
            float sq = v0 * v0 + v1 * v1;
#pragma unroll
            for (int off = 1; off < 16; off <<= 1) {
                sv += __shfl_xor(sv, off, 64);
                sq += __shfl_xor(sq, off, 64);
            }
            if (l15 == 0) {
                atomicAdd(&st[2048 + slot * 128 + o], sv);
                atomicAdd(&st[4096 + slot * 128 + o], sq);
            }
        }
    __syncthreads();

    // write 16 fragment-tiles (4 sf-tiles x 4 ci-chunks), each 1KB contiguous
    int sf0 = r0 & 511;
    int T0 = sf0 >> 4;
    int q  = r0 >> 9;
    for (int e = tid; e < 1024; e += 256) {
        int ft = e >> 6, ln = e & 63;
        int sfti = ft >> 2, cic = ft & 3;
        int row = sfti * 16 + (ln & 15);
        int col = cic * 32 + ((ln >> 4) << 3);
        short8v val = *reinterpret_cast<const short8v*>(&a2st[row * 136 + col]);
        size_t dst = (((size_t)(b * 32 + T0 + sfti) * 68) + (q * 4 + cic)) * 512 + ln * 8;
        *reinterpret_cast<short8v*>(zr2 + dst) = val;
    }
}

// in-place BN2 + ReLU on zr2. block = (b,sfT); thread owns fixed (c&3, lane) -> fixed channels
__global__ __launch_bounds__(256) void k_bn2(__hip_bfloat16* __restrict__ z,
                                             const float* __restrict__ sc2,
                                             const float* __restrict__ sh2) {
    int tid = threadIdx.x;
    int ln = tid & 63, c0 = tid >> 6;
    int ch0 = ((c0 * 32) + ((ln >> 4) << 3)) & 127;
    float sc[8], sh[8];
#pragma unroll
    for (int j = 0; j < 8; ++j) { sc[j] = sc2[ch0 + j]; sh[j] = sh2[ch0 + j]; }
    size_t base = (size_t)blockIdx.x * 68 * 512 + (size_t)ln * 8;
#pragma unroll 4
    for (int j = 0; j < 17; ++j) {
        int c = c0 + j * 4;
        __hip_bfloat16* p = z + base + (size_t)c * 512;
        short8v v = *reinterpret_cast<const short8v*>(p);
        short8v r;
#pragma unroll
        for (int k = 0; k < 8; ++k) {
            unsigned u = ((unsigned)(unsigned short)v[k]) << 16;
            float f = __uint_as_float(u);
            float t = fmaxf(f * sc[k] + sh[k], 0.f);
            __hip_bfloat16 h = __float2bfloat16(t);
            r[k] = *reinterpret_cast<short*>(&h);
        }
        *reinterpret_cast<short8v*>(p) = r;
    }
}

__device__ __forceinline__ int4v shift_dn(int4v cur, int4v prev, int lane, bool zero_edge) {
    int l15 = lane & 15;
    int4v r;
#pragma unroll
    for (int j = 0; j < 4; ++j) {
        int a = __shfl(cur[j], lane - 1, 64);
        int b = __shfl(prev[j], lane + 15, 64);
        int v = (l15 == 0) ? b : a;
        r[j] = (zero_edge && l15 == 0) ? 0 : v;
    }
    return r;
}
__device__ __forceinline__ int4v shift_up(int4v cur, int4v next, int lane, bool zero_edge) {
    int l15 = lane & 15;
    int4v r;
#pragma unroll
    for (int j = 0; j < 4; ++j) {
        int a = __shfl(cur[j], lane + 1, 64);
        int b = __shfl(next[j], lane - 15, 64);
        int v = (l15 == 15) ? b : a;
        r[j] = (zero_edge && l15 == 15) ? 0 : v;
    }
    return r;
}

// MFMA temporal conv on fragment-tiled layouts. Block 128o x 64sf (one b), 4 waves 2m x 2n.
__global__ __launch_bounds__(256) void k_conv_mfma(const __hip_bfloat16* __restrict__ zr2,
                                                   const __hip_bfloat16* __restrict__ wkt2,
                                                   const float* __restrict__ bt,
                                                   float* __restrict__ cp,
                                                   float* __restrict__ s3,
                                                   float* __restrict__ ss3) {
    int tid = threadIdx.x;
    int bi = blockIdx.x;
    int b = bi >> 3;
    int s0 = (bi & 7) << 6;
    int wid = tid >> 6, lane = tid & 63;
    int l15 = lane & 15, l4 = lane >> 4;
    int m0 = (wid >> 1) * 64;
    int n0 = s0 + (wid & 1) * 32;
    int T = n0 >> 4;                         // 0..30
    int Tm1 = (T > 0) ? T - 1 : 0;
    int Tp2 = (T + 2 < 32) ? T + 2 : 31;
    bool zlo = (n0 == 0);
    bool zhi = (n0 + 32 == 512);

    const __hip_bfloat16* zb = zr2 + ((size_t)(b * 32)) * 68 * 512 + (size_t)lane * 8;
    const __hip_bfloat16* pBm1 = zb + (size_t)Tm1 * 68 * 512;
    const __hip_bfloat16* pB0  = zb + (size_t)T * 68 * 512;
    const __hip_bfloat16* pB1  = zb + (size_t)(T + 1) * 68 * 512;
    const __hip_bfloat16* pB2  = zb + (size_t)Tp2 * 68 * 512;

    int mT = m0 >> 4;
    const __hip_bfloat16* pA = wkt2 + (size_t)lane * 8;

    f32x4 acc[4][2];
#pragma unroll
    for (int mi = 0; mi < 4; ++mi)
#pragma unroll
        for (int ni = 0; ni < 2; ++ni) acc[mi][ni] = (f32x4){0.f, 0.f, 0.f, 0.f};

    for (int c = 0; c < 68; ++c) {
        size_t co = (size_t)c * 512;
        int4v a_[3][4];
#pragma unroll
        for (int k = 0; k < 3; ++k)
#pragma unroll
            for (int mi = 0; mi < 4; ++mi)
                a_[k][mi] = ld16(pA + ((size_t)((k * 8 + mT + mi) * 68) * 512 + co));

        int4v bm1 = ld16(pBm1 + co);
        int4v b0  = ld16(pB0 + co);
        int4v b1  = ld16(pB1 + co);
        int4v b2  = ld16(pB2 + co);

        int4v bf[3][2];
        bf[1][0] = b0;
        bf[1][1] = b1;
        bf[0][0] = shift_dn(b0, bm1, lane, zlo);
        bf[0][1] = shift_dn(b1, b0, lane, false);
        bf[2][0] = shift_up(b0, b1, lane, false);
        bf[2][1] = shift_up(b1, b2, lane, zhi);

#pragma unroll
        for (int k = 0; k < 3; ++k)
#pragma unroll
            for (int mi = 0; mi < 4; ++mi)
#pragma unroll
                for (int ni = 0; ni < 2; ++ni)
                    acc[mi][ni] = mfma16(a_[k][mi], bf[k][ni], acc[mi][ni]);
    }

    int slot = bi & 15;
#pragma unroll
    for (int mi = 0; mi < 4; ++mi)
#pragma unroll
        for (int r = 0; r < 4; ++r) {
            int o = m0 + mi * 16 + l4 * 4 + r;
            float btv = bt[o];
            float v0 = acc[mi][0][r] + btv;
            float v1 = acc[mi][1][r] + btv;
            size_t cb = ((size_t)(b * 128 + o)) * 512 + n0 + l15;
            cp[cb] = v0;
            cp[cb + 16] = v1;
            float sv = v0 + v1;
            float sq = v0 * v0 + v1 * v1;
#pragma unroll
            for (int off = 1; off < 16; off <<= 1) {
                sv += __shfl_xor(sv, off, 64);
                sq += __shfl_xor(sq, off, 64);
            }
            if (l15 == 0) {
                atomicAdd(&s3[slot * 128 + o], sv);
                atomicAdd(&ss3[slot * 128 + o], sq);
            }
        }
}

__global__ __launch_bounds__(256) void k_out(const float* __restrict__ cp,
                                             const float* __restrict__ sc3,
                                             const float* __restrict__ sh3,
                                             float* __restrict__ out) {
    __shared__ float tile[128 * 33];
    int tid = threadIdx.x;
    int b = blockIdx.x >> 4;
    int t0 = (blockIdx.x & 15) * 32;
    for (int e = tid; e < 128 * 32; e += 256) {
        int o = e >> 5, tj = e & 31;
        tile[o * 33 + tj] = cp[((size_t)b * 128 + o) * 512 + t0 + tj];
    }
    __syncthreads();
    for (int e = tid; e < 128 * 32; e += 256) {
        int o = e & 127, th = e >> 7;
        float v = tile[o * 33 + th] * sc3[o] + sh3[o];
        out[((size_t)b * 512 + t0 + th) * 128 + o] = fmaxf(v, 0.f);
    }
}

extern "C" void kernel_launch(void* const* d_in, const int* in_sizes, int n_in,
                              void* d_out, int out_size, void* d_ws, size_t ws_size,
                              hipStream_t stream) {
    const float* x   = (const float*)d_in[0];
    const float* adj = (const float*)d_in[1];
    const float* w1  = (const float*)d_in[2];
    const float* b1  = (const float*)d_in[3];
    const float* g1  = (const float*)d_in[4];
    const float* be1 = (const float*)d_in[5];
    const float* w2  = (const float*)d_in[6];
    const float* b2  = (const float*)d_in[7];
    const float* g2  = (const float*)d_in[8];
    const float* be2 = (const float*)d_in[9];
    const float* wt  = (const float*)d_in[10];
    const float* bt  = (const float*)d_in[11];
    const float* gt  = (const float*)d_in[12];
    const float* bet = (const float*)d_in[13];
    float* out = (float*)d_out;

    char* ws = (char*)d_ws;
    __hip_bfloat16* zr2  = (__hip_bfloat16*)(ws + OFF_ZR);
    __hip_bfloat16* wkt2 = (__hip_bfloat16*)(ws + OFF_WKT);
    __hip_bfloat16* w2b  = (__hip_bfloat16*)(ws + OFF_W2B);
    float* cp = (float*)(ws + OFF_CP);
    float* st = (float*)(ws + OFF_ST);

    hipMemsetAsync(st, 0, 10240 * sizeof(float), stream);

    k_wt_bf16<<<dim3(3264), dim3(256), 0, stream>>>(wt, wkt2);
    k_w2b<<<dim3(32), dim3(256), 0, stream>>>(w2, w2b);
    k_stats1<<<dim3(1024), dim3(256), 0, stream>>>(x, adj, w1, b1, st);
    k_finalize<<<dim3(1), dim3(128), 0, stream>>>(st, st + 1024, g1, be1,
                                                  st + 10240, st + 10304, 64, 1.f / 557056.f);
    k_gcn<<<dim3(8704), dim3(256), 0, stream>>>(x, adj, w1, b1,
                                                st + 10240, st + 10304,
                                                w2b, b2, st, zr2);
    k_finalize<<<dim3(1), dim3(128), 0, stream>>>(st + 2048, st + 4096, g2, be2,
                                                  st + 10368, st + 10496, 128, 1.f / 557056.f);
    k_bn2<<<dim3(2048), dim3(256), 0, stream>>>(zr2, st + 10368, st + 10496);
    k_conv_mfma<<<dim3(512), dim3(256), 0, stream>>>(zr2, wkt2, bt,
                                                     cp, st + 6144, st + 8192);
    k_finalize<<<dim3(1), dim3(128), 0, stream>>>(st + 6144, st + 8192, gt, bet,
                                                  st + 10624, st + 10752, 128, 1.f / 32768.f);
    k_out<<<dim3(1024), dim3(256), 0, stream>>>(cp, st + 10624, st + 10752, out);
}

// Round 8
// 375.290 us; speedup vs baseline: 4.7146x; 1.1063x over previous
//
#include <hip/hip_runtime.h>
#include <hip/hip_bf16.h>

#define EPS 1e-5f

static constexpr int Bv = 64, Tv = 512, Vv = 17, Hv = 128;
static constexpr int CHv = Hv * Vv;                // 2176
static constexpr long ZBv = (long)CHv * Tv;        // 1114112 elems per batch

typedef __attribute__((ext_vector_type(8))) short short8v;
typedef __attribute__((ext_vector_type(4))) float f32x4;
typedef __attribute__((ext_vector_type(4))) int   int4v;

// ---- workspace layout (~161 MB) ----
// zr2: fragment-tiled bf16 [b][sfT(32)][ciC(68)][lane(64)][e(8)]  (PRE-BN2 values)
//      holds z[b][sf = sfT*16 + (lane&15)][ci' = ciC*32 + (lane>>4)*8 + e]
// wkt2: fragment-tiled bf16 [k(3)][oT(8)][ciC(68)][lane(64)][e(8)]
static constexpr size_t SZ_Z    = (size_t)Bv * (size_t)ZBv * 2;      // 142,606,336
static constexpr size_t OFF_ZR  = 0;
static constexpr size_t OFF_WKT = OFF_ZR + SZ_Z;
static constexpr size_t SZ_WKT  = (size_t)3 * 128 * 2176 * 2;        // 1,671,168
static constexpr size_t OFF_W2B = OFF_WKT + SZ_WKT;                   // bf16 w2 [128][64]
static constexpr size_t SZ_W2B  = (size_t)128 * 64 * 2;
static constexpr size_t OFF_CP  = OFF_W2B + SZ_W2B;                   // f32 conv out [b][o][sf]
static constexpr size_t SZ_CP   = (size_t)Bv * Hv * Tv * 4;          // 16,777,216
static constexpr size_t OFF_ST  = OFF_CP + SZ_CP;
// stats floats:
//  0:s1sp[1024] 1024:ss1sp 2048:s2sp[2048] 4096:ss2sp 6144:s3sp[2048] 8192:ss3sp
//  10240:sc1[64] 10304:sh1[64] 10368:sc2[128] 10496:sh2[128] 10624:sc3[128] 10752:sh3[128]

__device__ __forceinline__ int4v ld16(const __hip_bfloat16* p) {
    return *reinterpret_cast<const int4v*>(p);
}
__device__ __forceinline__ f32x4 mfma16(int4v a, int4v b, f32x4 c) {
    return __builtin_amdgcn_mfma_f32_16x16x32_bf16(
        *reinterpret_cast<short8v*>(&a), *reinterpret_cast<short8v*>(&b), c, 0, 0, 0);
}
__device__ __forceinline__ float bf2f(short s) {
    return __uint_as_float(((unsigned)(unsigned short)s) << 16);
}

__global__ __launch_bounds__(256) void k_wt_bf16(const float* __restrict__ wt,
                                                 __hip_bfloat16* __restrict__ wkt2) {
    int i = blockIdx.x * 256 + threadIdx.x;
    if (i >= 3 * 128 * 2176) return;
    int el = i & 7;
    int ln = (i >> 3) & 63;
    int r  = i >> 9;            // ((k*8 + oT)*68 + c)
    int c  = r % 68; r /= 68;
    int oT = r & 7;  int k = r >> 3;
    int o   = oT * 16 + (ln & 15);
    int cip = c * 32 + ((ln >> 4) << 3) + el;
    int q = cip >> 7, o_in = cip & 127;
    wkt2[i] = __float2bfloat16(wt[(size_t)o * 6528 + (o_in * 17 + q) * 3 + k]);
}

__global__ __launch_bounds__(256) void k_w2b(const float* __restrict__ w2,
                                             __hip_bfloat16* __restrict__ w2b) {
    int e = blockIdx.x * 256 + threadIdx.x;
    if (e >= 8192) return;
    w2b[e] = __float2bfloat16(w2[e]);
}

__global__ __launch_bounds__(256) void k_stats1(const float* __restrict__ x,
                                                const float* __restrict__ adj,
                                                const float* __restrict__ w1,
                                                const float* __restrict__ b1,
                                                float* __restrict__ st) {
    __shared__ float adj_s[289];
    __shared__ float xs[32 * 34];
    __shared__ float mix[32 * 34];
    __shared__ float red[256], red2[256];
    int tid = threadIdx.x;
    int n0 = blockIdx.x * 32;
    for (int i = tid; i < 289; i += 256) adj_s[i] = adj[i];
    for (int i = tid; i < 1088; i += 256) xs[i] = x[(size_t)n0 * 34 + i];
    __syncthreads();
    for (int e = tid; e < 1088; e += 256) {
        int n = e / 34, r = e % 34;
        int w = r >> 1, c = r & 1;
        float acc = 0.f;
        for (int v = 0; v < 17; ++v) acc += xs[n * 34 + v * 2 + c] * adj_s[v * 17 + w];
        mix[n * 34 + w * 2 + c] = acc;
    }
    __syncthreads();
    int o = tid & 63, g = tid >> 6;
    float w0 = w1[o * 2], w1v = w1[o * 2 + 1], bb = b1[o];
    float s = 0.f, s2 = 0.f;
    for (int n = g; n < 32; n += 4)
        for (int v = 0; v < 17; ++v) {
            float a = mix[n * 34 + v * 2] * w0 + mix[n * 34 + v * 2 + 1] * w1v + bb;
            s += a; s2 += a * a;
        }
    red[tid] = s; red2[tid] = s2;
    __syncthreads();
    if (tid < 64) {
        float S  = red[tid] + red[tid + 64] + red[tid + 128] + red[tid + 192];
        float S2 = red2[tid] + red2[tid + 64] + red2[tid + 128] + red2[tid + 192];
        int slot = blockIdx.x & 15;
        atomicAdd(&st[slot * 64 + o], S);
        atomicAdd(&st[1024 + slot * 64 + o], S2);
    }
}

__global__ void k_finalize(const float* __restrict__ sums, const float* __restrict__ sumsq,
                           const float* __restrict__ gamma, const float* __restrict__ beta,
                           float* __restrict__ scale, float* __restrict__ shift,
                           int count, float inv_denom) {
    int o = threadIdx.x;
    if (o >= count) return;
    float S = 0.f, Q = 0.f;
    for (int j = 0; j < 16; ++j) { S += sums[j * count + o]; Q += sumsq[j * count + o]; }
    float m = S * inv_denom;
    float var = Q * inv_denom - m * m;
    float rstd = rsqrtf(var + EPS);
    float sc = rstd * gamma[o];
    scale[o] = sc;
    shift[o] = beta[o] - m * sc;
}

// MFMA GCN: block = (b, 64 folded rows tv=r0..r0+63). 4 waves.
// LDS union: {h1b[85][88] bf16 + m2b[64][88] bf16} then a2st[64][136] bf16.
__global__ __launch_bounds__(256) void k_gcn(const float* __restrict__ x,
                                             const float* __restrict__ adj,
                                             const float* __restrict__ w1,
                                             const float* __restrict__ b1,
                                             const float* __restrict__ sc1,
                                             const float* __restrict__ sh1,
                                             const __hip_bfloat16* __restrict__ w2b,
                                             const float* __restrict__ b2,
                                             float* __restrict__ st,
                                             __hip_bfloat16* __restrict__ zr2) {
    __shared__ float adj_s[289];
    __shared__ float xs[170];
    __shared__ float mix1[170];
    __shared__ __align__(16) char uni[26240];
    __hip_bfloat16* h1b  = reinterpret_cast<__hip_bfloat16*>(uni);           // [85][88]
    __hip_bfloat16* m2b  = reinterpret_cast<__hip_bfloat16*>(uni + 14976);   // [64][88]
    __hip_bfloat16* a2st = reinterpret_cast<__hip_bfloat16*>(uni);           // [64][136]

    int tid = threadIdx.x;
    int bi = blockIdx.x;
    int b = bi / 136, rb = bi - b * 136;
    int r0 = rb * 64;
    int t_lo = r0 / 17;

    for (int i = tid; i < 289; i += 256) adj_s[i] = adj[i];
    for (int i = tid; i < 170; i += 256) {
        int tt = i / 34, r = i - tt * 34;
        int t = min(t_lo + tt, 511);
        xs[i] = x[(size_t)(b * 512 + t) * 34 + r];
    }
    __syncthreads();

    // mix1 [5][34]
    for (int e = tid; e < 170; e += 256) {
        int n = e / 34, r = e % 34, w = r >> 1, c = r & 1;
        float acc = 0.f;
        for (int v = 0; v < 17; ++v) acc += xs[n * 34 + v * 2 + c] * adj_s[v * 17 + w];
        mix1[n * 34 + w * 2 + c] = acc;
    }
    __syncthreads();

    // h1b [85][88] bf16: relu(BN1(mix1 @ w1^T + b1))
    for (int e = tid; e < 85 * 64; e += 256) {
        int row = e >> 6, o = e & 63;
        int n = row / 17, v = row - n * 17;
        float a = mix1[n * 34 + v * 2] * w1[o * 2] + mix1[n * 34 + v * 2 + 1] * w1[o * 2 + 1] + b1[o];
        a = a * sc1[o] + sh1[o];
        h1b[row * 88 + o] = __float2bfloat16(fmaxf(a, 0.f));
    }
    __syncthreads();

    // mix2 rows r0..r0+63 -> m2b bf16 [64][88]; thread = (row j, 16-ch chunk)
    {
        int j = tid >> 2, cq = (tid & 3) << 4;
        int tv = r0 + j;
        int t = tv / 17, w = tv - t * 17;
        int base = (t - t_lo) * 17;
        float a[16];
#pragma unroll
        for (int i = 0; i < 16; ++i) a[i] = 0.f;
        for (int v = 0; v < 17; ++v) {
            float ad = adj_s[v * 17 + w];
            short8v p0 = *reinterpret_cast<const short8v*>(&h1b[(base + v) * 88 + cq]);
            short8v p1 = *reinterpret_cast<const short8v*>(&h1b[(base + v) * 88 + cq + 8]);
#pragma unroll
            for (int i = 0; i < 8; ++i) {
                a[i]     += ad * bf2f(p0[i]);
                a[i + 8] += ad * bf2f(p1[i]);
            }
        }
        __hip_bfloat16* mp = &m2b[j * 88 + cq];
#pragma unroll
        for (int i = 0; i < 16; ++i) mp[i] = __float2bfloat16(a[i]);
    }
    __syncthreads();

    // MFMA: a2[128 o][64 rows] = w2 @ mix2^T. Wave: 64 o x 32 rows.
    int wid = tid >> 6, lane = tid & 63;
    int l15 = lane & 15, l4 = lane >> 4;
    int m0 = (wid >> 1) * 64, nh = (wid & 1) * 32;

    short8v afr[4][2];
#pragma unroll
    for (int mi = 0; mi < 4; ++mi)
#pragma unroll
        for (int kk = 0; kk < 2; ++kk)
            afr[mi][kk] = *reinterpret_cast<const short8v*>(
                w2b + (size_t)(m0 + mi * 16 + l15) * 64 + kk * 32 + l4 * 8);

    f32x4 acc[4][2];
#pragma unroll
    for (int mi = 0; mi < 4; ++mi)
#pragma unroll
        for (int ni = 0; ni < 2; ++ni) acc[mi][ni] = (f32x4){0.f, 0.f, 0.f, 0.f};

#pragma unroll
    for (int kk = 0; kk < 2; ++kk)
#pragma unroll
        for (int ni = 0; ni < 2; ++ni) {
            short8v bfr = *reinterpret_cast<const short8v*>(
                &m2b[(nh + ni * 16 + l15) * 88 + kk * 32 + l4 * 8]);
#pragma unroll
            for (int mi = 0; mi < 4; ++mi)
                acc[mi][ni] = __builtin_amdgcn_mfma_f32_16x16x32_bf16(
                    afr[mi][kk], bfr, acc[mi][ni], 0, 0, 0);
        }
    __syncthreads();   // all m2b reads done before a2st (aliased) writes

    // epilogue: bias, stage a2 to LDS (bf16)
#pragma unroll
    for (int mi = 0; mi < 4; ++mi)
#pragma unroll
        for (int r = 0; r < 4; ++r) {
            int o = m0 + mi * 16 + l4 * 4 + r;
            float bb = b2[o];
            a2st[(nh + l15) * 136 + o]      = __float2bfloat16(acc[mi][0][r] + bb);
            a2st[(nh + 16 + l15) * 136 + o] = __float2bfloat16(acc[mi][1][r] + bb);
        }
    __syncthreads();

    // BN2 stats: column sums of a2st (bf16-rounded, negligible vs threshold)
    {
        int o = tid & 127, half = tid >> 7;
        float s = 0.f, q = 0.f;
        int j0 = half * 32;
#pragma unroll 8
        for (int j = j0; j < j0 + 32; ++j) {
            float v = bf2f(*reinterpret_cast<const short*>(&a2st[j * 136 + o]));
            s += v; q += v * v;
        }
        int slot = bi & 15;
        atomicAdd(&st[2048 + slot * 128 + o], s);
        atomicAdd(&st[4096 + slot * 128 + o], q);
    }

    // write 16 fragment-tiles (4 sf-tiles x 4 ci-chunks), each 1KB contiguous
    int sf0 = r0 & 511;
    int T0 = sf0 >> 4;
    int q  = r0 >> 9;
    __hip_bfloat16* zrb = zr2;
    for (int e = tid; e < 1024; e += 256) {
        int ft = e >> 6, ln = e & 63;
        int sfti = ft >> 2, cic = ft & 3;
        int row = sfti * 16 + (ln & 15);
        int col = cic * 32 + ((ln >> 4) << 3);
        short8v val = *reinterpret_cast<const short8v*>(&a2st[row * 136 + col]);
        size_t dst = (((size_t)(b * 32 + T0 + sfti) * 68) + (q * 4 + cic)) * 512 + ln * 8;
        *reinterpret_cast<short8v*>(zrb + dst) = val;
    }
}

// apply BN2+ReLU in f32 to a raw bf16 fragment, repack to bf16
__device__ __forceinline__ int4v bnrelu(int4v raw, const float* scr, const float* shr) {
    int4v out;
#pragma unroll
    for (int j = 0; j < 4; ++j) {
        unsigned w = (unsigned)raw[j];
        float lo = __uint_as_float(w << 16);
        float hi = __uint_as_float(w & 0xffff0000u);
        lo = fmaxf(lo * scr[2 * j] + shr[2 * j], 0.f);
        hi = fmaxf(hi * scr[2 * j + 1] + shr[2 * j + 1], 0.f);
        __hip_bfloat16 l = __float2bfloat16(lo), h = __float2bfloat16(hi);
        out[j] = (int)((((unsigned)*reinterpret_cast<unsigned short*>(&h)) << 16) |
                       (unsigned)*reinterpret_cast<unsigned short*>(&l));
    }
    return out;
}

// MFMA temporal conv with fused BN2+ReLU on the B path.
// Block 128o x 64sf (one b), 4 waves 2m x 2n. Taps are direct per-lane-addressed loads.
__global__ __launch_bounds__(256, 3) void k_conv_mfma(const __hip_bfloat16* __restrict__ zr2,
                                                      const __hip_bfloat16* __restrict__ wkt2,
                                                      const float* __restrict__ sc2,
                                                      const float* __restrict__ sh2,
                                                      const float* __restrict__ bt,
                                                      float* __restrict__ cp,
                                                      float* __restrict__ s3,
                                                      float* __restrict__ ss3) {
    __shared__ float scs[128], shs[128];
    int tid = threadIdx.x;
    if (tid < 128) { scs[tid] = sc2[tid]; shs[tid] = sh2[tid]; }
    __syncthreads();

    int bi = blockIdx.x;
    int b = bi >> 3;
    int s0 = (bi & 7) << 6;
    int wid = tid >> 6, lane = tid & 63;
    int l15 = lane & 15, l4 = lane >> 4;
    int m0 = (wid >> 1) * 64;
    int n0 = s0 + (wid & 1) * 32;
    int mT = m0 >> 4;

    // 6 tap offsets (elements) + validity
    size_t toff[3][2];
    bool tok[3][2];
#pragma unroll
    for (int k = 0; k < 3; ++k)
#pragma unroll
        for (int ni = 0; ni < 2; ++ni) {
            int srow = n0 + ni * 16 + l15 + k - 1;
            bool ok = (unsigned)srow < 512u;
            int rc = ok ? srow : (srow < 0 ? 0 : 511);
            toff[k][ni] = ((size_t)(b * 32 + (rc >> 4)) * 68) * 512
                        + (size_t)((l4 * 16 + (rc & 15)) * 8);
            tok[k][ni] = ok;
        }

    const __hip_bfloat16* pA = wkt2 + (size_t)lane * 8;

    f32x4 acc[4][2];
#pragma unroll
    for (int mi = 0; mi < 4; ++mi)
#pragma unroll
        for (int ni = 0; ni < 2; ++ni) acc[mi][ni] = (f32x4){0.f, 0.f, 0.f, 0.f};

    for (int c = 0; c < 68; ++c) {
        size_t co = (size_t)c * 512;
        // per-lane BN constants for this c-phase
        float scr[8], shr[8];
        {
            const float* sp = &scs[((c & 3) << 5) + l4 * 8];
            const float* hp = &shs[((c & 3) << 5) + l4 * 8];
#pragma unroll
            for (int j = 0; j < 8; ++j) { scr[j] = sp[j]; shr[j] = hp[j]; }
        }
        int4v a_[3][4];
#pragma unroll
        for (int k = 0; k < 3; ++k)
#pragma unroll
            for (int mi = 0; mi < 4; ++mi)
                a_[k][mi] = ld16(pA + ((size_t)((k * 8 + mT + mi) * 68) * 512 + co));

        int4v braw[3][2];
#pragma unroll
        for (int k = 0; k < 3; ++k)
#pragma unroll
            for (int ni = 0; ni < 2; ++ni)
                braw[k][ni] = ld16(zr2 + toff[k][ni] + co);

        int4v bfr[3][2];
#pragma unroll
        for (int k = 0; k < 3; ++k)
#pragma unroll
            for (int ni = 0; ni < 2; ++ni) {
                int4v v = bnrelu(braw[k][ni], scr, shr);
                if (!tok[k][ni]) v = (int4v){0, 0, 0, 0};
                bfr[k][ni] = v;
            }

#pragma unroll
        for (int k = 0; k < 3; ++k)
#pragma unroll
            for (int mi = 0; mi < 4; ++mi)
#pragma unroll
                for (int ni = 0; ni < 2; ++ni)
                    acc[mi][ni] = mfma16(a_[k][mi], bfr[k][ni], acc[mi][ni]);
    }

    int slot = bi & 15;
#pragma unroll
    for (int mi = 0; mi < 4; ++mi)
#pragma unroll
        for (int r = 0; r < 4; ++r) {
            int o = m0 + mi * 16 + l4 * 4 + r;
            float btv = bt[o];
            float v0 = acc[mi][0][r] + btv;
            float v1 = acc[mi][1][r] + btv;
            size_t cb = ((size_t)(b * 128 + o)) * 512 + n0 + l15;
            cp[cb] = v0;
            cp[cb + 16] = v1;
            float sv = v0 + v1;
            float sq = v0 * v0 + v1 * v1;
#pragma unroll
            for (int off = 1; off < 16; off <<= 1) {
                sv += __shfl_xor(sv, off, 64);
                sq += __shfl_xor(sq, off, 64);
            }
            if (l15 == 0) {
                atomicAdd(&s3[slot * 128 + o], sv);
                atomicAdd(&ss3[slot * 128 + o], sq);
            }
        }
}

__global__ __launch_bounds__(256) void k_out(const float* __restrict__ cp,
                                             const float* __restrict__ sc3,
                                             const float* __restrict__ sh3,
                                             float* __restrict__ out) {
    __shared__ float tile[128 * 33];
    int tid = threadIdx.x;
    int b = blockIdx.x >> 4;
    int t0 = (blockIdx.x & 15) * 32;
    for (int e = tid; e < 128 * 32; e += 256) {
        int o = e >> 5, tj = e & 31;
        tile[o * 33 + tj] = cp[((size_t)b * 128 + o) * 512 + t0 + tj];
    }
    __syncthreads();
    for (int e = tid; e < 128 * 32; e += 256) {
        int o = e & 127, th = e >> 7;
        float v = tile[o * 33 + th] * sc3[o] + sh3[o];
        out[((size_t)b * 512 + t0 + th) * 128 + o] = fmaxf(v, 0.f);
    }
}

extern "C" void kernel_launch(void* const* d_in, const int* in_sizes, int n_in,
                              void* d_out, int out_size, void* d_ws, size_t ws_size,
                              hipStream_t stream) {
    const float* x   = (const float*)d_in[0];
    const float* adj = (const float*)d_in[1];
    const float* w1  = (const float*)d_in[2];
    const float* b1  = (const float*)d_in[3];
    const float* g1  = (const float*)d_in[4];
    const float* be1 = (const float*)d_in[5];
    const float* w2  = (const float*)d_in[6];
    const float* b2  = (const float*)d_in[7];
    const float* g2  = (const float*)d_in[8];
    const float* be2 = (const float*)d_in[9];
    const float* wt  = (const float*)d_in[10];
    const float* bt  = (const float*)d_in[11];
    const float* gt  = (const float*)d_in[12];
    const float* bet = (const float*)d_in[13];
    float* out = (float*)d_out;

    char* ws = (char*)d_ws;
    __hip_bfloat16* zr2  = (__hip_bfloat16*)(ws + OFF_ZR);
    __hip_bfloat16* wkt2 = (__hip_bfloat16*)(ws + OFF_WKT);
    __hip_bfloat16* w2b  = (__hip_bfloat16*)(ws + OFF_W2B);
    float* cp = (float*)(ws + OFF_CP);
    float* st = (float*)(ws + OFF_ST);

    hipMemsetAsync(st, 0, 10240 * sizeof(float), stream);

    k_wt_bf16<<<dim3(3264), dim3(256), 0, stream>>>(wt, wkt2);
    k_w2b<<<dim3(32), dim3(256), 0, stream>>>(w2, w2b);
    k_stats1<<<dim3(1024), dim3(256), 0, stream>>>(x, adj, w1, b1, st);
    k_finalize<<<dim3(1), dim3(128), 0, stream>>>(st, st + 1024, g1, be1,
                                                  st + 10240, st + 10304, 64, 1.f / 557056.f);
    k_gcn<<<dim3(8704), dim3(256), 0, stream>>>(x, adj, w1, b1,
                                                st + 10240, st + 10304,
                                                w2b, b2, st, zr2);
    k_finalize<<<dim3(1), dim3(128), 0, stream>>>(st + 2048, st + 4096, g2, be2,
                                                  st + 10368, st + 10496, 128, 1.f / 557056.f);
    k_conv_mfma<<<dim3(512), dim3(256), 0, stream>>>(zr2, wkt2,
                                                     st + 10368, st + 10496, bt,
                                                     cp, st + 6144, st + 8192);
    k_finalize<<<dim3(1), dim3(128), 0, stream>>>(st + 6144, st + 8192, gt, bet,
                                                  st + 10624, st + 10752, 128, 1.f / 32768.f);
    k_out<<<dim3(1024), dim3(256), 0, stream>>>(cp, st + 10624, st + 10752, out);
}

// Round 9
// 272.631 us; speedup vs baseline: 6.4898x; 1.3766x over previous
//
#include <hip/hip_runtime.h>
#include <hip/hip_bf16.h>

#define EPS 1e-5f

static constexpr int Bv = 64, Tv = 512, Vv = 17, Hv = 128;
static constexpr int CHv = Hv * Vv;                // 2176
static constexpr long ZBv = (long)CHv * Tv;        // 1114112 elems per batch

typedef __attribute__((ext_vector_type(8))) short short8v;
typedef __attribute__((ext_vector_type(4))) float f32x4;
typedef __attribute__((ext_vector_type(4))) int   int4v;

// ---- workspace layout (~161 MB) ----
// zr2: fragment-tiled bf16 [b][sfT(32)][ciC(68)][lane(64)][e(8)]  (PRE-BN2 values)
// wkt2: fragment-tiled bf16 [k(3)][oT(8)][ciC(68)][lane(64)][e(8)]
static constexpr size_t SZ_Z    = (size_t)Bv * (size_t)ZBv * 2;      // 142,606,336
static constexpr size_t OFF_ZR  = 0;
static constexpr size_t OFF_WKT = OFF_ZR + SZ_Z;
static constexpr size_t SZ_WKT  = (size_t)3 * 128 * 2176 * 2;        // 1,671,168
static constexpr size_t OFF_W2B = OFF_WKT + SZ_WKT;                   // bf16 w2 [128][64]
static constexpr size_t SZ_W2B  = (size_t)128 * 64 * 2;
static constexpr size_t OFF_CP  = OFF_W2B + SZ_W2B;                   // f32 conv out [b][o][sf]
static constexpr size_t SZ_CP   = (size_t)Bv * Hv * Tv * 4;          // 16,777,216
static constexpr size_t OFF_ST  = OFF_CP + SZ_CP;
// stats floats:
//  0:s1sp[1024] 1024:ss1sp 2048:s2sp[2048] 4096:ss2sp 6144:s3sp[2048] 8192:ss3sp
//  10240:sc1[64] 10304:sh1[64] 10368:sc2[128] 10496:sh2[128] 10624:sc3[128] 10752:sh3[128]

__device__ __forceinline__ int4v ld16(const __hip_bfloat16* p) {
    return *reinterpret_cast<const int4v*>(p);
}
__device__ __forceinline__ f32x4 mfma16(int4v a, int4v b, f32x4 c) {
    return __builtin_amdgcn_mfma_f32_16x16x32_bf16(
        *reinterpret_cast<short8v*>(&a), *reinterpret_cast<short8v*>(&b), c, 0, 0, 0);
}
__device__ __forceinline__ float bf2f(short s) {
    return __uint_as_float(((unsigned)(unsigned short)s) << 16);
}

__global__ __launch_bounds__(256) void k_wt_bf16(const float* __restrict__ wt,
                                                 __hip_bfloat16* __restrict__ wkt2) {
    int i = blockIdx.x * 256 + threadIdx.x;
    if (i >= 3 * 128 * 2176) return;
    int el = i & 7;
    int ln = (i >> 3) & 63;
    int r  = i >> 9;            // ((k*8 + oT)*68 + c)
    int c  = r % 68; r /= 68;
    int oT = r & 7;  int k = r >> 3;
    int o   = oT * 16 + (ln & 15);
    int cip = c * 32 + ((ln >> 4) << 3) + el;
    int q = cip >> 7, o_in = cip & 127;
    wkt2[i] = __float2bfloat16(wt[(size_t)o * 6528 + (o_in * 17 + q) * 3 + k]);
}

__global__ __launch_bounds__(256) void k_w2b(const float* __restrict__ w2,
                                             __hip_bfloat16* __restrict__ w2b) {
    int e = blockIdx.x * 256 + threadIdx.x;
    if (e >= 8192) return;
    w2b[e] = __float2bfloat16(w2[e]);
}

__global__ __launch_bounds__(256) void k_stats1(const float* __restrict__ x,
                                                const float* __restrict__ adj,
                                                const float* __restrict__ w1,
                                                const float* __restrict__ b1,
                                                float* __restrict__ st) {
    __shared__ float adj_s[289];
    __shared__ float xs[32 * 34];
    __shared__ float mix[32 * 34];
    __shared__ float red[256], red2[256];
    int tid = threadIdx.x;
    int n0 = blockIdx.x * 32;
    for (int i = tid; i < 289; i += 256) adj_s[i] = adj[i];
    for (int i = tid; i < 1088; i += 256) xs[i] = x[(size_t)n0 * 34 + i];
    __syncthreads();
    for (int e = tid; e < 1088; e += 256) {
        int n = e / 34, r = e % 34;
        int w = r >> 1, c = r & 1;
        float acc = 0.f;
        for (int v = 0; v < 17; ++v) acc += xs[n * 34 + v * 2 + c] * adj_s[v * 17 + w];
        mix[n * 34 + w * 2 + c] = acc;
    }
    __syncthreads();
    int o = tid & 63, g = tid >> 6;
    float w0 = w1[o * 2], w1v = w1[o * 2 + 1], bb = b1[o];
    float s = 0.f, s2 = 0.f;
    for (int n = g; n < 32; n += 4)
        for (int v = 0; v < 17; ++v) {
            float a = mix[n * 34 + v * 2] * w0 + mix[n * 34 + v * 2 + 1] * w1v + bb;
            s += a; s2 += a * a;
        }
    red[tid] = s; red2[tid] = s2;
    __syncthreads();
    if (tid < 64) {
        float S  = red[tid] + red[tid + 64] + red[tid + 128] + red[tid + 192];
        float S2 = red2[tid] + red2[tid + 64] + red2[tid + 128] + red2[tid + 192];
        int slot = blockIdx.x & 15;
        atomicAdd(&st[slot * 64 + o], S);
        atomicAdd(&st[1024 + slot * 64 + o], S2);
    }
}

__global__ void k_finalize(const float* __restrict__ sums, const float* __restrict__ sumsq,
                           const float* __restrict__ gamma, const float* __restrict__ beta,
                           float* __restrict__ scale, float* __restrict__ shift,
                           int count, float inv_denom) {
    int o = threadIdx.x;
    if (o >= count) return;
    float S = 0.f, Q = 0.f;
    for (int j = 0; j < 16; ++j) { S += sums[j * count + o]; Q += sumsq[j * count + o]; }
    float m = S * inv_denom;
    float var = Q * inv_denom - m * m;
    float rstd = rsqrtf(var + EPS);
    float sc = rstd * gamma[o];
    scale[o] = sc;
    shift[o] = beta[o] - m * sc;
}

// MFMA GCN: block = (b, 64 folded rows tv=r0..r0+63). 4 waves.
__global__ __launch_bounds__(256) void k_gcn(const float* __restrict__ x,
                                             const float* __restrict__ adj,
                                             const float* __restrict__ w1,
                                             const float* __restrict__ b1,
                                             const float* __restrict__ sc1,
                                             const float* __restrict__ sh1,
                                             const __hip_bfloat16* __restrict__ w2b,
                                             const float* __restrict__ b2,
                                             float* __restrict__ st,
                                             __hip_bfloat16* __restrict__ zr2) {
    __shared__ float adj_s[289];
    __shared__ float xs[170];
    __shared__ float mix1[170];
    __shared__ __align__(16) char uni[26240];
    __hip_bfloat16* h1b  = reinterpret_cast<__hip_bfloat16*>(uni);           // [85][88]
    __hip_bfloat16* m2b  = reinterpret_cast<__hip_bfloat16*>(uni + 14976);   // [64][88]
    __hip_bfloat16* a2st = reinterpret_cast<__hip_bfloat16*>(uni);           // [64][136]

    int tid = threadIdx.x;
    int bi = blockIdx.x;
    int b = bi / 136, rb = bi - b * 136;
    int r0 = rb * 64;
    int t_lo = r0 / 17;

    for (int i = tid; i < 289; i += 256) adj_s[i] = adj[i];
    for (int i = tid; i < 170; i += 256) {
        int tt = i / 34, r = i - tt * 34;
        int t = min(t_lo + tt, 511);
        xs[i] = x[(size_t)(b * 512 + t) * 34 + r];
    }
    __syncthreads();

    for (int e = tid; e < 170; e += 256) {
        int n = e / 34, r = e % 34, w = r >> 1, c = r & 1;
        float acc = 0.f;
        for (int v = 0; v < 17; ++v) acc += xs[n * 34 + v * 2 + c] * adj_s[v * 17 + w];
        mix1[n * 34 + w * 2 + c] = acc;
    }
    __syncthreads();

    for (int e = tid; e < 85 * 64; e += 256) {
        int row = e >> 6, o = e & 63;
        int n = row / 17, v = row - n * 17;
        float a = mix1[n * 34 + v * 2] * w1[o * 2] + mix1[n * 34 + v * 2 + 1] * w1[o * 2 + 1] + b1[o];
        a = a * sc1[o] + sh1[o];
        h1b[row * 88 + o] = __float2bfloat16(fmaxf(a, 0.f));
    }
    __syncthreads();

    {
        int j = tid >> 2, cq = (tid & 3) << 4;
        int tv = r0 + j;
        int t = tv / 17, w = tv - t * 17;
        int base = (t - t_lo) * 17;
        float a[16];
#pragma unroll
        for (int i = 0; i < 16; ++i) a[i] = 0.f;
        for (int v = 0; v < 17; ++v) {
            float ad = adj_s[v * 17 + w];
            short8v p0 = *reinterpret_cast<const short8v*>(&h1b[(base + v) * 88 + cq]);
            short8v p1 = *reinterpret_cast<const short8v*>(&h1b[(base + v) * 88 + cq + 8]);
#pragma unroll
            for (int i = 0; i < 8; ++i) {
                a[i]     += ad * bf2f(p0[i]);
                a[i + 8] += ad * bf2f(p1[i]);
            }
        }
        __hip_bfloat16* mp = &m2b[j * 88 + cq];
#pragma unroll
        for (int i = 0; i < 16; ++i) mp[i] = __float2bfloat16(a[i]);
    }
    __syncthreads();

    int wid = tid >> 6, lane = tid & 63;
    int l15 = lane & 15, l4 = lane >> 4;
    int m0 = (wid >> 1) * 64, nh = (wid & 1) * 32;

    short8v afr[4][2];
#pragma unroll
    for (int mi = 0; mi < 4; ++mi)
#pragma unroll
        for (int kk = 0; kk < 2; ++kk)
            afr[mi][kk] = *reinterpret_cast<const short8v*>(
                w2b + (size_t)(m0 + mi * 16 + l15) * 64 + kk * 32 + l4 * 8);

    f32x4 acc[4][2];
#pragma unroll
    for (int mi = 0; mi < 4; ++mi)
#pragma unroll
        for (int ni = 0; ni < 2; ++ni) acc[mi][ni] = (f32x4){0.f, 0.f, 0.f, 0.f};

#pragma unroll
    for (int kk = 0; kk < 2; ++kk)
#pragma unroll
        for (int ni = 0; ni < 2; ++ni) {
            short8v bfr = *reinterpret_cast<const short8v*>(
                &m2b[(nh + ni * 16 + l15) * 88 + kk * 32 + l4 * 8]);
#pragma unroll
            for (int mi = 0; mi < 4; ++mi)
                acc[mi][ni] = __builtin_amdgcn_mfma_f32_16x16x32_bf16(
                    afr[mi][kk], bfr, acc[mi][ni], 0, 0, 0);
        }
    __syncthreads();   // all m2b reads done before a2st (aliased) writes

#pragma unroll
    for (int mi = 0; mi < 4; ++mi)
#pragma unroll
        for (int r = 0; r < 4; ++r) {
            int o = m0 + mi * 16 + l4 * 4 + r;
            float bb = b2[o];
            a2st[(nh + l15) * 136 + o]      = __float2bfloat16(acc[mi][0][r] + bb);
            a2st[(nh + 16 + l15) * 136 + o] = __float2bfloat16(acc[mi][1][r] + bb);
        }
    __syncthreads();

    {
        int o = tid & 127, half = tid >> 7;
        float s = 0.f, q = 0.f;
        int j0 = half * 32;
#pragma unroll 8
        for (int j = j0; j < j0 + 32; ++j) {
            float v = bf2f(*reinterpret_cast<const short*>(&a2st[j * 136 + o]));
            s += v; q += v * v;
        }
        int slot = bi & 15;
        atomicAdd(&st[2048 + slot * 128 + o], s);
        atomicAdd(&st[4096 + slot * 128 + o], q);
    }

    int sf0 = r0 & 511;
    int T0 = sf0 >> 4;
    int q  = r0 >> 9;
    for (int e = tid; e < 1024; e += 256) {
        int ft = e >> 6, ln = e & 63;
        int sfti = ft >> 2, cic = ft & 3;
        int row = sfti * 16 + (ln & 15);
        int col = cic * 32 + ((ln >> 4) << 3);
        short8v val = *reinterpret_cast<const short8v*>(&a2st[row * 136 + col]);
        size_t dst = (((size_t)(b * 32 + T0 + sfti) * 68) + (q * 4 + cic)) * 512 + ln * 8;
        *reinterpret_cast<short8v*>(zr2 + dst) = val;
    }
}

// apply BN2+ReLU in f32 to a raw bf16 fragment, repack via v_cvt_pk_bf16_f32
__device__ __forceinline__ int4v bnrelu(int4v raw, const float* scr, const float* shr) {
    int4v out;
#pragma unroll
    for (int j = 0; j < 4; ++j) {
        unsigned w = (unsigned)raw[j];
        float lo = __uint_as_float(w << 16);
        float hi = __uint_as_float(w & 0xffff0000u);
        lo = fmaxf(lo * scr[2 * j] + shr[2 * j], 0.f);
        hi = fmaxf(hi * scr[2 * j + 1] + shr[2 * j + 1], 0.f);
        __hip_bfloat162 p = __float22bfloat162_rn(make_float2(lo, hi));
        out[j] = *reinterpret_cast<int*>(&p);
    }
    return out;
}

// MFMA temporal conv, fused BN2+ReLU. Block = 64o x 64sf (one b), 4 waves of 32o x 32sf.
// Grid 1024 -> 4 blocks/CU (16 waves/CU). All 12 loads batched per c-iter.
__global__ __launch_bounds__(256, 2) void k_conv_mfma(const __hip_bfloat16* __restrict__ zr2,
                                                      const __hip_bfloat16* __restrict__ wkt2,
                                                      const float* __restrict__ sc2,
                                                      const float* __restrict__ sh2,
                                                      const float* __restrict__ bt,
                                                      float* __restrict__ cp,
                                                      float* __restrict__ s3,
                                                      float* __restrict__ ss3) {
    __shared__ float scs[128], shs[128];
    int tid = threadIdx.x;
    if (tid < 128) { scs[tid] = sc2[tid]; shs[tid] = sh2[tid]; }
    __syncthreads();

    int bi = blockIdx.x;
    int b  = bi >> 4;
    int rr = bi & 15;
    int oB = (rr >> 3) << 6;       // 0 or 64
    int sB = (rr & 7) << 6;        // sf base
    int wid = tid >> 6, lane = tid & 63;
    int l15 = lane & 15, l4 = lane >> 4;
    int m0 = oB + (wid >> 1) * 32;
    int n0 = sB + (wid & 1) * 32;
    int mT = m0 >> 4;

    // 6 tap element-offsets (int, fits: < 71.4M) + validity
    int toffE[3][2];
    bool tok[3][2];
#pragma unroll
    for (int k = 0; k < 3; ++k)
#pragma unroll
        for (int ni = 0; ni < 2; ++ni) {
            int srow = n0 + ni * 16 + l15 + k - 1;
            bool ok = (unsigned)srow < 512u;
            int rc = ok ? srow : (srow < 0 ? 0 : 511);
            toffE[k][ni] = ((b * 32 + (rc >> 4)) * 68) * 512 + ((l4 * 16 + (rc & 15)) * 8);
            tok[k][ni] = ok;
        }
    int aoffE[3][2];
#pragma unroll
    for (int k = 0; k < 3; ++k)
#pragma unroll
        for (int mi = 0; mi < 2; ++mi)
            aoffE[k][mi] = ((k * 8 + mT + mi) * 68) * 512 + lane * 8;

    f32x4 acc[2][2];
#pragma unroll
    for (int mi = 0; mi < 2; ++mi)
#pragma unroll
        for (int ni = 0; ni < 2; ++ni) acc[mi][ni] = (f32x4){0.f, 0.f, 0.f, 0.f};

    for (int c = 0; c < 68; ++c) {
        int co = c << 9;
        // BN consts for this phase (LDS broadcast)
        float scr[8], shr[8];
        {
            const float* sp = &scs[((c & 3) << 5) + l4 * 8];
            const float* hp = &shs[((c & 3) << 5) + l4 * 8];
#pragma unroll
            for (int j = 0; j < 8; ++j) { scr[j] = sp[j]; shr[j] = hp[j]; }
        }
        // issue ALL loads (B taps first, then A), pin with sched_barrier
        int4v braw[3][2], a_[3][2];
#pragma unroll
        for (int k = 0; k < 3; ++k)
#pragma unroll
            for (int ni = 0; ni < 2; ++ni)
                braw[k][ni] = ld16(zr2 + toffE[k][ni] + co);
#pragma unroll
        for (int k = 0; k < 3; ++k)
#pragma unroll
            for (int mi = 0; mi < 2; ++mi)
                a_[k][mi] = ld16(wkt2 + aoffE[k][mi] + co);
        __builtin_amdgcn_sched_barrier(0);
        // consume in issue order
#pragma unroll
        for (int k = 0; k < 3; ++k)
#pragma unroll
            for (int ni = 0; ni < 2; ++ni) {
                int4v v = bnrelu(braw[k][ni], scr, shr);
                if (!tok[k][ni]) v = (int4v){0, 0, 0, 0};
#pragma unroll
                for (int mi = 0; mi < 2; ++mi)
                    acc[mi][ni] = mfma16(a_[k][mi], v, acc[mi][ni]);
            }
    }

    int slot = bi & 15;
#pragma unroll
    for (int mi = 0; mi < 2; ++mi)
#pragma unroll
        for (int r = 0; r < 4; ++r) {
            int o = m0 + mi * 16 + l4 * 4 + r;
            float btv = bt[o];
            float v0 = acc[mi][0][r] + btv;
            float v1 = acc[mi][1][r] + btv;
            size_t cb = ((size_t)(b * 128 + o)) * 512 + n0 + l15;
            cp[cb] = v0;
            cp[cb + 16] = v1;
            float sv = v0 + v1;
            float sq = v0 * v0 + v1 * v1;
#pragma unroll
            for (int off = 1; off < 16; off <<= 1) {
                sv += __shfl_xor(sv, off, 64);
                sq += __shfl_xor(sq, off, 64);
            }
            if (l15 == 0) {
                atomicAdd(&s3[slot * 128 + o], sv);
                atomicAdd(&ss3[slot * 128 + o], sq);
            }
        }
}

__global__ __launch_bounds__(256) void k_out(const float* __restrict__ cp,
                                             const float* __restrict__ sc3,
                                             const float* __restrict__ sh3,
                                             float* __restrict__ out) {
    __shared__ float tile[128 * 33];
    int tid = threadIdx.x;
    int b = blockIdx.x >> 4;
    int t0 = (blockIdx.x & 15) * 32;
    for (int e = tid; e < 128 * 32; e += 256) {
        int o = e >> 5, tj = e & 31;
        tile[o * 33 + tj] = cp[((size_t)b * 128 + o) * 512 + t0 + tj];
    }
    __syncthreads();
    for (int e = tid; e < 128 * 32; e += 256) {
        int o = e & 127, th = e >> 7;
        float v = tile[o * 33 + th] * sc3[o] + sh3[o];
        out[((size_t)b * 512 + t0 + th) * 128 + o] = fmaxf(v, 0.f);
    }
}

extern "C" void kernel_launch(void* const* d_in, const int* in_sizes, int n_in,
                              void* d_out, int out_size, void* d_ws, size_t ws_size,
                              hipStream_t stream) {
    const float* x   = (const float*)d_in[0];
    const float* adj = (const float*)d_in[1];
    const float* w1  = (const float*)d_in[2];
    const float* b1  = (const float*)d_in[3];
    const float* g1  = (const float*)d_in[4];
    const float* be1 = (const float*)d_in[5];
    const float* w2  = (const float*)d_in[6];
    const float* b2  = (const float*)d_in[7];
    const float* g2  = (const float*)d_in[8];
    const float* be2 = (const float*)d_in[9];
    const float* wt  = (const float*)d_in[10];
    const float* bt  = (const float*)d_in[11];
    const float* gt  = (const float*)d_in[12];
    const float* bet = (const float*)d_in[13];
    float* out = (float*)d_out;

    char* ws = (char*)d_ws;
    __hip_bfloat16* zr2  = (__hip_bfloat16*)(ws + OFF_ZR);
    __hip_bfloat16* wkt2 = (__hip_bfloat16*)(ws + OFF_WKT);
    __hip_bfloat16* w2b  = (__hip_bfloat16*)(ws + OFF_W2B);
    float* cp = (float*)(ws + OFF_CP);
    float* st = (float*)(ws + OFF_ST);

    hipMemsetAsync(st, 0, 10240 * sizeof(float), stream);

    k_wt_bf16<<<dim3(3264), dim3(256), 0, stream>>>(wt, wkt2);
    k_w2b<<<dim3(32), dim3(256), 0, stream>>>(w2, w2b);
    k_stats1<<<dim3(1024), dim3(256), 0, stream>>>(x, adj, w1, b1, st);
    k_finalize<<<dim3(1), dim3(128), 0, stream>>>(st, st + 1024, g1, be1,
                                                  st + 10240, st + 10304, 64, 1.f / 557056.f);
    k_gcn<<<dim3(8704), dim3(256), 0, stream>>>(x, adj, w1, b1,
                                                st + 10240, st + 10304,
                                                w2b, b2, st, zr2);
    k_finalize<<<dim3(1), dim3(128), 0, stream>>>(st + 2048, st + 4096, g2, be2,
                                                  st + 10368, st + 10496, 128, 1.f / 557056.f);
    k_conv_mfma<<<dim3(1024), dim3(256), 0, stream>>>(zr2, wkt2,
                                                      st + 10368, st + 10496, bt,
                                                      cp, st + 6144, st + 8192);
    k_finalize<<<dim3(1), dim3(128), 0, stream>>>(st + 6144, st + 8192, gt, bet,
                                                  st + 10624, st + 10752, 128, 1.f / 32768.f);
    k_out<<<dim3(1024), dim3(256), 0, stream>>>(cp, st + 10624, st + 10752, out);
}

// Round 10
// 202.475 us; speedup vs baseline: 8.7385x; 1.3465x over previous
//
#include <hip/hip_runtime.h>
#include <hip/hip_bf16.h>

#define EPS 1e-5f

static constexpr int Bv = 64, Tv = 512, Vv = 17, Hv = 128;
static constexpr int CHv = Hv * Vv;                // 2176
static constexpr long ZBv = (long)CHv * Tv;        // 1114112 elems per batch

typedef __attribute__((ext_vector_type(8))) short short8v;
typedef __attribute__((ext_vector_type(4))) float f32x4;
typedef __attribute__((ext_vector_type(4))) int   int4v;

// ---- workspace layout (~161 MB) ----
// zr2: fragment-tiled bf16 [b][sfT(32)][ciC(68)][lane(64)][e(8)]  (PRE-BN2 values)
// wkt2: fragment-tiled bf16 [k(3)][oT(8)][ciC(68)][lane(64)][e(8)]
static constexpr size_t SZ_Z    = (size_t)Bv * (size_t)ZBv * 2;      // 142,606,336
static constexpr size_t OFF_ZR  = 0;
static constexpr size_t OFF_WKT = OFF_ZR + SZ_Z;
static constexpr size_t SZ_WKT  = (size_t)3 * 128 * 2176 * 2;        // 1,671,168
static constexpr size_t OFF_W2B = OFF_WKT + SZ_WKT;                   // bf16 w2 [128][64]
static constexpr size_t SZ_W2B  = (size_t)128 * 64 * 2;
static constexpr size_t OFF_CP  = OFF_W2B + SZ_W2B;                   // f32 conv out [b][o][sf]
static constexpr size_t SZ_CP   = (size_t)Bv * Hv * Tv * 4;          // 16,777,216
static constexpr size_t OFF_ST  = OFF_CP + SZ_CP;
// stats floats:
//  0:s1sp[1024] 1024:ss1sp 2048:s2sp[2048] 4096:ss2sp 6144:s3sp[2048] 8192:ss3sp
//  10240:sc1[64] 10304:sh1[64] 10368:sc2[128] 10496:sh2[128] 10624:sc3[128] 10752:sh3[128]

__device__ __forceinline__ int4v ld16(const __hip_bfloat16* p) {
    return *reinterpret_cast<const int4v*>(p);
}
__device__ __forceinline__ f32x4 mfma16(int4v a, int4v b, f32x4 c) {
    return __builtin_amdgcn_mfma_f32_16x16x32_bf16(
        *reinterpret_cast<short8v*>(&a), *reinterpret_cast<short8v*>(&b), c, 0, 0, 0);
}
__device__ __forceinline__ float bf2f(short s) {
    return __uint_as_float(((unsigned)(unsigned short)s) << 16);
}

__global__ __launch_bounds__(256) void k_wt_bf16(const float* __restrict__ wt,
                                                 __hip_bfloat16* __restrict__ wkt2) {
    int i = blockIdx.x * 256 + threadIdx.x;
    if (i >= 3 * 128 * 2176) return;
    int el = i & 7;
    int ln = (i >> 3) & 63;
    int r  = i >> 9;            // ((k*8 + oT)*68 + c)
    int c  = r % 68; r /= 68;
    int oT = r & 7;  int k = r >> 3;
    int o   = oT * 16 + (ln & 15);
    int cip = c * 32 + ((ln >> 4) << 3) + el;
    int q = cip >> 7, o_in = cip & 127;
    wkt2[i] = __float2bfloat16(wt[(size_t)o * 6528 + (o_in * 17 + q) * 3 + k]);
}

__global__ __launch_bounds__(256) void k_w2b(const float* __restrict__ w2,
                                             __hip_bfloat16* __restrict__ w2b) {
    int e = blockIdx.x * 256 + threadIdx.x;
    if (e >= 8192) return;
    w2b[e] = __float2bfloat16(w2[e]);
}

__global__ __launch_bounds__(256) void k_stats1(const float* __restrict__ x,
                                                const float* __restrict__ adj,
                                                const float* __restrict__ w1,
                                                const float* __restrict__ b1,
                                                float* __restrict__ st) {
    __shared__ float adj_s[289];
    __shared__ float xs[32 * 34];
    __shared__ float mix[32 * 34];
    __shared__ float red[256], red2[256];
    int tid = threadIdx.x;
    int n0 = blockIdx.x * 32;
    for (int i = tid; i < 289; i += 256) adj_s[i] = adj[i];
    for (int i = tid; i < 1088; i += 256) xs[i] = x[(size_t)n0 * 34 + i];
    __syncthreads();
    for (int e = tid; e < 1088; e += 256) {
        int n = e / 34, r = e % 34;
        int w = r >> 1, c = r & 1;
        float acc = 0.f;
        for (int v = 0; v < 17; ++v) acc += xs[n * 34 + v * 2 + c] * adj_s[v * 17 + w];
        mix[n * 34 + w * 2 + c] = acc;
    }
    __syncthreads();
    int o = tid & 63, g = tid >> 6;
    float w0 = w1[o * 2], w1v = w1[o * 2 + 1], bb = b1[o];
    float s = 0.f, s2 = 0.f;
    for (int n = g; n < 32; n += 4)
        for (int v = 0; v < 17; ++v) {
            float a = mix[n * 34 + v * 2] * w0 + mix[n * 34 + v * 2 + 1] * w1v + bb;
            s += a; s2 += a * a;
        }
    red[tid] = s; red2[tid] = s2;
    __syncthreads();
    if (tid < 64) {
        float S  = red[tid] + red[tid + 64] + red[tid + 128] + red[tid + 192];
        float S2 = red2[tid] + red2[tid + 64] + red2[tid + 128] + red2[tid + 192];
        int slot = blockIdx.x & 15;
        atomicAdd(&st[slot * 64 + o], S);
        atomicAdd(&st[1024 + slot * 64 + o], S2);
    }
}

__global__ void k_finalize(const float* __restrict__ sums, const float* __restrict__ sumsq,
                           const float* __restrict__ gamma, const float* __restrict__ beta,
                           float* __restrict__ scale, float* __restrict__ shift,
                           int count, float inv_denom) {
    int o = threadIdx.x;
    if (o >= count) return;
    float S = 0.f, Q = 0.f;
    for (int j = 0; j < 16; ++j) { S += sums[j * count + o]; Q += sumsq[j * count + o]; }
    float m = S * inv_denom;
    float var = Q * inv_denom - m * m;
    float rstd = rsqrtf(var + EPS);
    float sc = rstd * gamma[o];
    scale[o] = sc;
    shift[o] = beta[o] - m * sc;
}

// MFMA GCN: block = (b, 64 folded rows tv=r0..r0+63). 4 waves.
__global__ __launch_bounds__(256) void k_gcn(const float* __restrict__ x,
                                             const float* __restrict__ adj,
                                             const float* __restrict__ w1,
                                             const float* __restrict__ b1,
                                             const float* __restrict__ sc1,
                                             const float* __restrict__ sh1,
                                             const __hip_bfloat16* __restrict__ w2b,
                                             const float* __restrict__ b2,
                                             float* __restrict__ st,
                                             __hip_bfloat16* __restrict__ zr2) {
    __shared__ float adj_s[289];
    __shared__ float xs[170];
    __shared__ float mix1[170];
    __shared__ __align__(16) char uni[26240];
    __hip_bfloat16* h1b  = reinterpret_cast<__hip_bfloat16*>(uni);           // [85][88]
    __hip_bfloat16* m2b  = reinterpret_cast<__hip_bfloat16*>(uni + 14976);   // [64][88]
    __hip_bfloat16* a2st = reinterpret_cast<__hip_bfloat16*>(uni);           // [64][136]

    int tid = threadIdx.x;
    int bi = blockIdx.x;
    int b = bi / 136, rb = bi - b * 136;
    int r0 = rb * 64;
    int t_lo = r0 / 17;

    for (int i = tid; i < 289; i += 256) adj_s[i] = adj[i];
    for (int i = tid; i < 170; i += 256) {
        int tt = i / 34, r = i - tt * 34;
        int t = min(t_lo + tt, 511);
        xs[i] = x[(size_t)(b * 512 + t) * 34 + r];
    }
    __syncthreads();

    for (int e = tid; e < 170; e += 256) {
        int n = e / 34, r = e % 34, w = r >> 1, c = r & 1;
        float acc = 0.f;
        for (int v = 0; v < 17; ++v) acc += xs[n * 34 + v * 2 + c] * adj_s[v * 17 + w];
        mix1[n * 34 + w * 2 + c] = acc;
    }
    __syncthreads();

    for (int e = tid; e < 85 * 64; e += 256) {
        int row = e >> 6, o = e & 63;
        int n = row / 17, v = row - n * 17;
        float a = mix1[n * 34 + v * 2] * w1[o * 2] + mix1[n * 34 + v * 2 + 1] * w1[o * 2 + 1] + b1[o];
        a = a * sc1[o] + sh1[o];
        h1b[row * 88 + o] = __float2bfloat16(fmaxf(a, 0.f));
    }
    __syncthreads();

    {
        int j = tid >> 2, cq = (tid & 3) << 4;
        int tv = r0 + j;
        int t = tv / 17, w = tv - t * 17;
        int base = (t - t_lo) * 17;
        float a[16];
#pragma unroll
        for (int i = 0; i < 16; ++i) a[i] = 0.f;
        for (int v = 0; v < 17; ++v) {
            float ad = adj_s[v * 17 + w];
            short8v p0 = *reinterpret_cast<const short8v*>(&h1b[(base + v) * 88 + cq]);
            short8v p1 = *reinterpret_cast<const short8v*>(&h1b[(base + v) * 88 + cq + 8]);
#pragma unroll
            for (int i = 0; i < 8; ++i) {
                a[i]     += ad * bf2f(p0[i]);
                a[i + 8] += ad * bf2f(p1[i]);
            }
        }
        __hip_bfloat16* mp = &m2b[j * 88 + cq];
#pragma unroll
        for (int i = 0; i < 16; ++i) mp[i] = __float2bfloat16(a[i]);
    }
    __syncthreads();

    int wid = tid >> 6, lane = tid & 63;
    int l15 = lane & 15, l4 = lane >> 4;
    int m0 = (wid >> 1) * 64, nh = (wid & 1) * 32;

    short8v afr[4][2];
#pragma unroll
    for (int mi = 0; mi < 4; ++mi)
#pragma unroll
        for (int kk = 0; kk < 2; ++kk)
            afr[mi][kk] = *reinterpret_cast<const short8v*>(
                w2b + (size_t)(m0 + mi * 16 + l15) * 64 + kk * 32 + l4 * 8);

    f32x4 acc[4][2];
#pragma unroll
    for (int mi = 0; mi < 4; ++mi)
#pragma unroll
        for (int ni = 0; ni < 2; ++ni) acc[mi][ni] = (f32x4){0.f, 0.f, 0.f, 0.f};

#pragma unroll
    for (int kk = 0; kk < 2; ++kk)
#pragma unroll
        for (int ni = 0; ni < 2; ++ni) {
            short8v bfr = *reinterpret_cast<const short8v*>(
                &m2b[(nh + ni * 16 + l15) * 88 + kk * 32 + l4 * 8]);
#pragma unroll
            for (int mi = 0; mi < 4; ++mi)
                acc[mi][ni] = __builtin_amdgcn_mfma_f32_16x16x32_bf16(
                    afr[mi][kk], bfr, acc[mi][ni], 0, 0, 0);
        }
    __syncthreads();   // all m2b reads done before a2st (aliased) writes

#pragma unroll
    for (int mi = 0; mi < 4; ++mi)
#pragma unroll
        for (int r = 0; r < 4; ++r) {
            int o = m0 + mi * 16 + l4 * 4 + r;
            float bb = b2[o];
            a2st[(nh + l15) * 136 + o]      = __float2bfloat16(acc[mi][0][r] + bb);
            a2st[(nh + 16 + l15) * 136 + o] = __float2bfloat16(acc[mi][1][r] + bb);
        }
    __syncthreads();

    {
        int o = tid & 127, half = tid >> 7;
        float s = 0.f, q = 0.f;
        int j0 = half * 32;
#pragma unroll 8
        for (int j = j0; j < j0 + 32; ++j) {
            float v = bf2f(*reinterpret_cast<const short*>(&a2st[j * 136 + o]));
            s += v; q += v * v;
        }
        int slot = bi & 15;
        atomicAdd(&st[2048 + slot * 128 + o], s);
        atomicAdd(&st[4096 + slot * 128 + o], q);
    }

    int sf0 = r0 & 511;
    int T0 = sf0 >> 4;
    int q  = r0 >> 9;
    for (int e = tid; e < 1024; e += 256) {
        int ft = e >> 6, ln = e & 63;
        int sfti = ft >> 2, cic = ft & 3;
        int row = sfti * 16 + (ln & 15);
        int col = cic * 32 + ((ln >> 4) << 3);
        short8v val = *reinterpret_cast<const short8v*>(&a2st[row * 136 + col]);
        size_t dst = (((size_t)(b * 32 + T0 + sfti) * 68) + (q * 4 + cic)) * 512 + ln * 8;
        *reinterpret_cast<short8v*>(zr2 + dst) = val;
    }
}

// apply BN2+ReLU in f32 to a raw bf16 fragment, repack via v_cvt_pk_bf16_f32
__device__ __forceinline__ int4v bnrelu(int4v raw, const float* scr, const float* shr) {
    int4v out;
#pragma unroll
    for (int j = 0; j < 4; ++j) {
        unsigned w = (unsigned)raw[j];
        float lo = __uint_as_float(w << 16);
        float hi = __uint_as_float(w & 0xffff0000u);
        lo = fmaxf(lo * scr[2 * j] + shr[2 * j], 0.f);
        hi = fmaxf(hi * scr[2 * j + 1] + shr[2 * j + 1], 0.f);
        __hip_bfloat162 p = __float22bfloat162_rn(make_float2(lo, hi));
        out[j] = *reinterpret_cast<int*>(&p);
    }
    return out;
}

// MFMA temporal conv. Block = 128o x 64sf (one b), 4 waves of 64o x 32sf, grid 512.
// B slab (rows sB-1..sB+64, 32ch) staged in LDS per c-iter with BN2+ReLU applied ONCE;
// taps via conflict-free ds_read_b128; 12 batched A loads/wave; 24 MFMA/wave.
__global__ __launch_bounds__(256, 2) void k_conv_mfma(const __hip_bfloat16* __restrict__ zr2,
                                                      const __hip_bfloat16* __restrict__ wkt2,
                                                      const float* __restrict__ sc2,
                                                      const float* __restrict__ sh2,
                                                      const float* __restrict__ bt,
                                                      float* __restrict__ cp,
                                                      float* __restrict__ s3,
                                                      float* __restrict__ ss3) {
    __shared__ float scs[128], shs[128];
    __shared__ __align__(16) __hip_bfloat16 zbuf[2][66][40];   // row stride 80B: 16B-aligned, bank-uniform

    int tid = threadIdx.x;
    if (tid < 128) { scs[tid] = sc2[tid]; shs[tid] = sh2[tid]; }

    int bi = blockIdx.x;
    int b  = bi >> 3;
    int sB = (bi & 7) << 6;
    int T  = sB >> 4;
    int wid = tid >> 6, lane = tid & 63;
    int l15 = lane & 15, l4 = lane >> 4;
    int m0 = (wid >> 1) * 64;
    int n0loc = (wid & 1) * 32;
    int mT = m0 >> 4;

    // staging geometry: main = one 16B frag-slice per thread (4 coalesced 1KB frags)
    int sf_f = tid >> 6;                        // fragment 0..3
    int srow = sf_f * 16 + l15 + 1;             // zbuf row
    int sch  = l4 * 8;                          // channel start within 32-chunk
    size_t smain = ((size_t)(b * 32 + T + sf_f) * 68) * 512 + (size_t)lane * 8;
    // edges: rows 0 (sf=sB-1) and 65 (sf=sB+64), 4 ch-groups each, threads 0..7
    bool has_edge = tid < 8;
    int er  = tid >> 2;                          // 0,1
    int elg = tid & 3;
    int esf = sB - 1 + er * 65;
    bool eok = (unsigned)esf < 512u;
    int erow = er * 65;
    size_t sedge = eok ? (((size_t)(b * 32 + (esf >> 4)) * 68) * 512
                          + (size_t)((elg * 16 + (esf & 15)) * 8)) : 0;

    // A offsets (12 fragments)
    int aoffE[3][4];
#pragma unroll
    for (int k = 0; k < 3; ++k)
#pragma unroll
        for (int mi = 0; mi < 4; ++mi)
            aoffE[k][mi] = ((k * 8 + mT + mi) * 68) * 512 + lane * 8;

    f32x4 acc[4][2];
#pragma unroll
    for (int mi = 0; mi < 4; ++mi)
#pragma unroll
        for (int ni = 0; ni < 2; ++ni) acc[mi][ni] = (f32x4){0.f, 0.f, 0.f, 0.f};

    __syncthreads();   // scs ready

    // prologue: stage c=0 into buf 0
    {
        int4v mr = ld16(zr2 + smain);
        float scr[8], shr[8];
        *reinterpret_cast<f32x4*>(scr)     = *reinterpret_cast<const f32x4*>(&scs[sch]);
        *reinterpret_cast<f32x4*>(scr + 4) = *reinterpret_cast<const f32x4*>(&scs[sch + 4]);
        *reinterpret_cast<f32x4*>(shr)     = *reinterpret_cast<const f32x4*>(&shs[sch]);
        *reinterpret_cast<f32x4*>(shr + 4) = *reinterpret_cast<const f32x4*>(&shs[sch + 4]);
        *reinterpret_cast<int4v*>(&zbuf[0][srow][sch]) = bnrelu(mr, scr, shr);
        if (has_edge) {
            int4v ev = (int4v){0, 0, 0, 0};
            if (eok) {
                int4v erv = ld16(zr2 + sedge);
                float escr[8], eshr[8];
                int ei = elg * 8;
                *reinterpret_cast<f32x4*>(escr)     = *reinterpret_cast<const f32x4*>(&scs[ei]);
                *reinterpret_cast<f32x4*>(escr + 4) = *reinterpret_cast<const f32x4*>(&scs[ei + 4]);
                *reinterpret_cast<f32x4*>(eshr)     = *reinterpret_cast<const f32x4*>(&shs[ei]);
                *reinterpret_cast<f32x4*>(eshr + 4) = *reinterpret_cast<const f32x4*>(&shs[ei + 4]);
                ev = bnrelu(erv, escr, eshr);
            }
            *reinterpret_cast<int4v*>(&zbuf[0][erow][elg * 8]) = ev;
        }
    }
    __syncthreads();

    int cur = 0;
    for (int c = 0; c < 68; ++c) {
        int c1 = c + 1;
        bool do_stage = c1 < 68;
        // --- issue stage loads for c+1 (longest dep chain) ---
        int4v mr = (int4v){0, 0, 0, 0}, erv = (int4v){0, 0, 0, 0};
        if (do_stage) {
            mr = ld16(zr2 + smain + ((size_t)c1 << 9));
            if (has_edge && eok) erv = ld16(zr2 + sedge + ((size_t)c1 << 9));
        }
        // --- issue A loads for c ---
        int4v a_[3][4];
#pragma unroll
        for (int k = 0; k < 3; ++k)
#pragma unroll
            for (int mi = 0; mi < 4; ++mi)
                a_[k][mi] = ld16(wkt2 + (size_t)aoffE[k][mi] + ((size_t)c << 9));
        // --- B taps from LDS ---
        int4v bf[3][2];
#pragma unroll
        for (int k = 0; k < 3; ++k)
#pragma unroll
            for (int ni = 0; ni < 2; ++ni) {
                int row = n0loc + 1 + ni * 16 + l15 + k - 1;
                bf[k][ni] = *reinterpret_cast<const int4v*>(&zbuf[cur][row][l4 * 8]);
            }
        __builtin_amdgcn_sched_barrier(0);
        // --- MFMA ---
#pragma unroll
        for (int k = 0; k < 3; ++k)
#pragma unroll
            for (int mi = 0; mi < 4; ++mi)
#pragma unroll
                for (int ni = 0; ni < 2; ++ni)
                    acc[mi][ni] = mfma16(a_[k][mi], bf[k][ni], acc[mi][ni]);
        // --- finish stage: bnrelu + ds_write into buf^1 ---
        if (do_stage) {
            int ph = (c1 & 3) << 5;
            float scr[8], shr[8];
            *reinterpret_cast<f32x4*>(scr)     = *reinterpret_cast<const f32x4*>(&scs[ph + sch]);
            *reinterpret_cast<f32x4*>(scr + 4) = *reinterpret_cast<const f32x4*>(&scs[ph + sch + 4]);
            *reinterpret_cast<f32x4*>(shr)     = *reinterpret_cast<const f32x4*>(&shs[ph + sch]);
            *reinterpret_cast<f32x4*>(shr + 4) = *reinterpret_cast<const f32x4*>(&shs[ph + sch + 4]);
            *reinterpret_cast<int4v*>(&zbuf[cur ^ 1][srow][sch]) = bnrelu(mr, scr, shr);
            if (has_edge) {
                int4v ev = (int4v){0, 0, 0, 0};
                if (eok) {
                    int ei = ph + elg * 8;
                    float escr[8], eshr[8];
                    *reinterpret_cast<f32x4*>(escr)     = *reinterpret_cast<const f32x4*>(&scs[ei]);
                    *reinterpret_cast<f32x4*>(escr + 4) = *reinterpret_cast<const f32x4*>(&scs[ei + 4]);
                    *reinterpret_cast<f32x4*>(eshr)     = *reinterpret_cast<const f32x4*>(&shs[ei]);
                    *reinterpret_cast<f32x4*>(eshr + 4) = *reinterpret_cast<const f32x4*>(&shs[ei + 4]);
                    ev = bnrelu(erv, escr, eshr);
                }
                *reinterpret_cast<int4v*>(&zbuf[cur ^ 1][erow][elg * 8]) = ev;
            }
        }
        __syncthreads();
        cur ^= 1;
    }

    int slot = bi & 15;
#pragma unroll
    for (int mi = 0; mi < 4; ++mi)
#pragma unroll
        for (int r = 0; r < 4; ++r) {
            int o = m0 + mi * 16 + l4 * 4 + r;
            float btv = bt[o];
            float v0 = acc[mi][0][r] + btv;
            float v1 = acc[mi][1][r] + btv;
            size_t cb = ((size_t)(b * 128 + o)) * 512 + sB + n0loc + l15;
            cp[cb] = v0;
            cp[cb + 16] = v1;
            float sv = v0 + v1;
            float sq = v0 * v0 + v1 * v1;
#pragma unroll
            for (int off = 1; off < 16; off <<= 1) {
                sv += __shfl_xor(sv, off, 64);
                sq += __shfl_xor(sq, off, 64);
            }
            if (l15 == 0) {
                atomicAdd(&s3[slot * 128 + o], sv);
                atomicAdd(&ss3[slot * 128 + o], sq);
            }
        }
}

__global__ __launch_bounds__(256) void k_out(const float* __restrict__ cp,
                                             const float* __restrict__ sc3,
                                             const float* __restrict__ sh3,
                                             float* __restrict__ out) {
    __shared__ float tile[128 * 33];
    int tid = threadIdx.x;
    int b = blockIdx.x >> 4;
    int t0 = (blockIdx.x & 15) * 32;
    for (int e = tid; e < 128 * 32; e += 256) {
        int o = e >> 5, tj = e & 31;
        tile[o * 33 + tj] = cp[((size_t)b * 128 + o) * 512 + t0 + tj];
    }
    __syncthreads();
    for (int e = tid; e < 128 * 32; e += 256) {
        int o = e & 127, th = e >> 7;
        float v = tile[o * 33 + th] * sc3[o] + sh3[o];
        out[((size_t)b * 512 + t0 + th) * 128 + o] = fmaxf(v, 0.f);
    }
}

extern "C" void kernel_launch(void* const* d_in, const int* in_sizes, int n_in,
                              void* d_out, int out_size, void* d_ws, size_t ws_size,
                              hipStream_t stream) {
    const float* x   = (const float*)d_in[0];
    const float* adj = (const float*)d_in[1];
    const float* w1  = (const float*)d_in[2];
    const float* b1  = (const float*)d_in[3];
    const float* g1  = (const float*)d_in[4];
    const float* be1 = (const float*)d_in[5];
    const float* w2  = (const float*)d_in[6];
    const float* b2  = (const float*)d_in[7];
    const float* g2  = (const float*)d_in[8];
    const float* be2 = (const float*)d_in[9];
    const float* wt  = (const float*)d_in[10];
    const float* bt  = (const float*)d_in[11];
    const float* gt  = (const float*)d_in[12];
    const float* bet = (const float*)d_in[13];
    float* out = (float*)d_out;

    char* ws = (char*)d_ws;
    __hip_bfloat16* zr2  = (__hip_bfloat16*)(ws + OFF_ZR);
    __hip_bfloat16* wkt2 = (__hip_bfloat16*)(ws + OFF_WKT);
    __hip_bfloat16* w2b  = (__hip_bfloat16*)(ws + OFF_W2B);
    float* cp = (float*)(ws + OFF_CP);
    float* st = (float*)(ws + OFF_ST);

    hipMemsetAsync(st, 0, 10240 * sizeof(float), stream);

    k_wt_bf16<<<dim3(3264), dim3(256), 0, stream>>>(wt, wkt2);
    k_w2b<<<dim3(32), dim3(256), 0, stream>>>(w2, w2b);
    k_stats1<<<dim3(1024), dim3(256), 0, stream>>>(x, adj, w1, b1, st);
    k_finalize<<<dim3(1), dim3(128), 0, stream>>>(st, st + 1024, g1, be1,
                                                  st + 10240, st + 10304, 64, 1.f / 557056.f);
    k_gcn<<<dim3(8704), dim3(256), 0, stream>>>(x, adj, w1, b1,
                                                st + 10240, st + 10304,
                                                w2b, b2, st, zr2);
    k_finalize<<<dim3(1), dim3(128), 0, stream>>>(st + 2048, st + 4096, g2, be2,
                                                  st + 10368, st + 10496, 128, 1.f / 557056.f);
    k_conv_mfma<<<dim3(512), dim3(256), 0, stream>>>(zr2, wkt2,
                                                     st + 10368, st + 10496, bt,
                                                     cp, st + 6144, st + 8192);
    k_finalize<<<dim3(1), dim3(128), 0, stream>>>(st + 6144, st + 8192, gt, bet,
                                                  st + 10624, st + 10752, 128, 1.f / 32768.f);
    k_out<<<dim3(1024), dim3(256), 0, stream>>>(cp, st + 10624, st + 10752, out);
}